// Round 16
// baseline (332.718 us; speedup 1.0000x reference)
//
#include <hip/hip_runtime.h>
#include <hip/hip_bf16.h>
#include <cmath>
#include <cstdint>

typedef __bf16 bf16;
typedef __bf16 bf16x8 __attribute__((ext_vector_type(8)));
typedef __bf16 bf16x4 __attribute__((ext_vector_type(4)));
typedef float  f32x4  __attribute__((ext_vector_type(4)));

#define EMBED 1024
#define FFDIM 4096
#define BATCH 4
#define SEQ   2048
#define MTOK  (BATCH*SEQ)

// ---------------- workspace layout ----------------
static constexpr size_t OFF_HB    = 0;              // 16MB bf16 hb (LN1 w; FF1,LN2 r)
static constexpr size_t OFF_XPE_B = 32ull << 20;    // 16MB bf16 xpeb (PE w; QKV,LN1 r)
static constexpr size_t OFF_Q     = 48ull << 20;    // Qb 16MB; then P 32MB (48-80); then ff1 bf16
static constexpr size_t OFF_K     = 64ull << 20;
static constexpr size_t OFF_VT    = 80ull << 20;    // 16MB bf16 [4][1024][2048]
static constexpr size_t OFF_E     = 96ull << 20;    // E bf16 32MB; then pv1 bf16; then T1 bf16 64MB
static constexpr size_t OFF_ATTN  = 160ull << 20;   // Vb 16MB; then pv0 bf16; then ff0 bf16
static constexpr size_t OFF_WQKVT = 224ull << 20;   // 6MB bf16 [3072][1024]
static constexpr size_t OFF_W1T   = 230ull << 20;   // 8MB
static constexpr size_t OFF_W2T   = 238ull << 20;   // 8MB

// ---------------- wait/barrier primitives ----------------
// r16: BARE sync, m201-style — no sched_barrier pins anywhere. Counted vmcnt
// asm keeps "memory" clobber (orders all memory ops incl. gload_lds); barriers
// are plain s_barrier so reg-only MFMA/VALU may pipeline across phases.
#define VMCNT6 { asm volatile("s_waitcnt vmcnt(6)" ::: "memory"); }
#define VMCNT8 { asm volatile("s_waitcnt vmcnt(8)" ::: "memory"); }
#define VMCNT0 { asm volatile("s_waitcnt vmcnt(0)" ::: "memory"); }
#define PH_BAR  { __builtin_amdgcn_s_barrier(); }
#define PH_END  { }
#define BARONLY { __builtin_amdgcn_s_barrier(); }

__device__ __forceinline__ void gload_lds16(const void* g, void* l) {
  __builtin_amdgcn_global_load_lds((const __attribute__((address_space(1))) void*)g,
                                   (__attribute__((address_space(3))) void*)l, 16, 0, 0);
}

// ---------------- PE add: xb = bf16(x + pe) ----------------
__global__ __launch_bounds__(256) void pe_add_kernel(const float* __restrict__ x,
                                                     bf16* __restrict__ xb) {
  int idx  = blockIdx.x * 256 + threadIdx.x;
  int pair = idx & 511;
  int s    = idx >> 9;
  float div = __expf((float)(2 * pair) * (-9.210340371976184f / (float)EMBED));
  float ang = (float)s * div;
  float sv = sinf(ang), cv = cosf(ang);
#pragma unroll
  for (int b = 0; b < BATCH; ++b) {
    size_t base = ((size_t)(b * SEQ + s)) * EMBED + (size_t)pair * 2;
    xb[base]     = (bf16)(x[base] + sv);
    xb[base + 1] = (bf16)(x[base + 1] + cv);
  }
}

// ---------------- weight transpose fp32[K][N] -> bf16[N][K] ----------------
__global__ __launch_bounds__(256) void transpose_kernel(const float* __restrict__ W,
                                                        bf16* __restrict__ Wt,
                                                        int K, int N) {
  __shared__ float tile[32][33];
  int nb = blockIdx.x * 32, kb = blockIdx.y * 32;
  int tx = threadIdx.x, ty = threadIdx.y;   // 32x8
#pragma unroll
  for (int i = 0; i < 32; i += 8)
    tile[ty + i][tx] = W[(size_t)(kb + ty + i) * N + nb + tx];
  __syncthreads();
#pragma unroll
  for (int i = 0; i < 32; i += 8)
    Wt[(size_t)(nb + ty + i) * K + kb + tx] = (bf16)tile[tx][ty + i];
}

// ---------------- V transpose bf16 [b][s][d] -> [b][d][s] ----------------
__global__ __launch_bounds__(256) void vtrans_kernel(const bf16* __restrict__ V,
                                                     bf16* __restrict__ VT) {
  __shared__ ushort tile[32][36];
  const int d0 = blockIdx.x * 32, s0 = blockIdx.y * 32, b = blockIdx.z;
  const ushort* src = (const ushort*)V + ((size_t)b * SEQ + s0) * EMBED + d0;
  ushort* dst = (ushort*)VT + ((size_t)b * EMBED + d0) * SEQ + s0;
  const int tx = threadIdx.x, ty = threadIdx.y;   // 32x8
#pragma unroll
  for (int i = 0; i < 32; i += 8)
    tile[ty + i][tx] = src[(size_t)(ty + i) * EMBED + tx];
  __syncthreads();
#pragma unroll
  for (int i = 0; i < 32; i += 8)
    dst[(size_t)(ty + i) * SEQ + tx] = tile[tx][ty + i];
}

// ---------------- gemm8: 256x256 tile, 8 waves (2Mx4N), 8-phase counted-vmcnt ----------------
// r14 epilogue + r16 bare-sync (m201 primitive set).
// EPI 5: bf16 *scale (+batch +split-K)  EPI 3: bf16 +bias relu  EPI 6: fused QKV row-major +bias
#define BMX 256
#define BNX 256
#define BKX 64

#define MM16(QR, QC, FB) { \
  __builtin_amdgcn_s_setprio(1); \
  _Pragma("unroll") for (int kk = 0; kk < 2; ++kk) \
  _Pragma("unroll") for (int i2 = 0; i2 < 4; ++i2) \
  _Pragma("unroll") for (int j2 = 0; j2 < 2; ++j2) \
    acc[(QR)*4 + i2][(QC)*2 + j2] = __builtin_amdgcn_mfma_f32_16x16x32_bf16( \
        fa[kk][i2], FB[kk][j2], acc[(QR)*4 + i2][(QC)*2 + j2], 0, 0, 0); \
  __builtin_amdgcn_s_setprio(0); }

template <int EPI>
__global__ __launch_bounds__(512, 2) void gemm8_kernel(
    const bf16* __restrict__ A, const bf16* __restrict__ B,
    const float* __restrict__ bias, void* __restrict__ out,
    int K, int lda, int ldb, int ldo, int NB,
    long long sAz, long long sBz, long long sOz,
    long long sAk, long long sBk, long long sOk,
    float scale,
    const float* bias2, const float* bias3, void* out2, void* out3) {
  __shared__ __align__(16) char ldsbuf[131072];
  char* const ldsA = ldsbuf;            // 2buf x 32KB
  char* const ldsB = ldsbuf + 65536;    // 2buf x 32KB

  // T1: bijective XCD-chunked swizzle + grouped raster (G=8)
  const int gx = gridDim.x, gy = gridDim.y;
  int id = blockIdx.x + gx * (blockIdx.y + gy * blockIdx.z);
  const int nwg = gx * gy * gridDim.z;
  const int qd = nwg >> 3, rm = nwg & 7;
  const int xcd = id & 7, pos = id >> 3;
  const int lid = (xcd < rm ? xcd * (qd + 1) : rm * (qd + 1) + (xcd - rm) * qd) + pos;
  const int per = gx * gy;
  const int tz = lid / per;
  const int s2 = lid - tz * per;
  const int G = 8;
  const int ngrp = G * gy;
  const int grp = s2 / ngrp;
  const int within = s2 - grp * ngrp;
  const int gwf = gx - grp * G;
  const int gw = gwf < G ? gwf : G;
  const int tx = grp * G + within % gw;
  const int ty = within / gw;

  const int zb = tz % NB;
  const int kh = tz / NB;
  A += (long long)zb * sAz + (long long)kh * sAk;
  B += (long long)zb * sBz + (long long)kh * sBk;

  const int tid  = threadIdx.x;
  const int wave = tid >> 6;
  const int lane = tid & 63;
  const int wm = wave >> 2, wn = wave & 3;   // 2M x 4N
  const int rowBase = ty * BMX;
  const int colBase = tx * BNX;
  const int lr = lane & 15;
  const int g  = lane >> 4;
  const int lx = lr & 7;

  // staging: thread t -> rr = t>>3, slot (t&7)^(rr&7) (src pre-swizzled, rule 21)
  const int rr = tid >> 3;
  const int slot = (tid & 7) ^ (rr & 7);
  const bf16* Abase = A + (long long)(rowBase + rr) * lda + slot * 8;
  const bf16* Bb0 = B + (long long)(colBase + (rr & 31) + ((rr >> 5)) * 64) * ldb + slot * 8;
  const bf16* Bb1 = B + (long long)(colBase + (rr & 31) + (2 + (rr >> 5)) * 64) * ldb + slot * 8;

  auto stA = [&](int T, int bufOff, int qr) {
    char* dst = ldsA + bufOff + qr * 16384 + wave * 1024;
    const bf16* s = Abase + (long long)(qr * 64) * lda + (long long)T * BKX;
    gload_lds16(s, dst);
    gload_lds16(s + (long long)128 * lda, dst + 8192);
  };
  auto stB = [&](int T, int bufOff, int qc) {
    char* dst = ldsB + bufOff + qc * 16384 + wave * 1024;
    const long long off = (long long)(qc * 32) * ldb + (long long)T * BKX;
    gload_lds16(Bb0 + off, dst);
    gload_lds16(Bb1 + off, dst + 8192);
  };

  bf16x8 fa[2][4], fbq0[2][2], fbq1[2][2];
  auto rdFA = [&](int bufOff, int qr) {
    const char* base = ldsA + bufOff + qr * 16384 + wm * 8192;
#pragma unroll
    for (int kk = 0; kk < 2; ++kk) {
      const int sw = ((kk * 4 + g) ^ lx) << 4;
#pragma unroll
      for (int i2 = 0; i2 < 4; ++i2)
        fa[kk][i2] = *(const bf16x8*)(base + (i2 * 16 + lr) * 128 + sw);
    }
  };
  auto rdFB = [&](int bufOff, int qc, bf16x8 fb[2][2]) {
    const char* base = ldsB + bufOff + qc * 16384 + wn * 4096;
#pragma unroll
    for (int kk = 0; kk < 2; ++kk) {
      const int sw = ((kk * 4 + g) ^ lx) << 4;
#pragma unroll
      for (int j2 = 0; j2 < 2; ++j2)
        fb[kk][j2] = *(const bf16x8*)(base + (j2 * 16 + lr) * 128 + sw);
    }
  };

  const f32x4 zero4 = {0.f, 0.f, 0.f, 0.f};
  f32x4 acc[8][4];
#pragma unroll
  for (int i = 0; i < 8; ++i)
#pragma unroll
    for (int j = 0; j < 4; ++j) acc[i][j] = zero4;

  const int nK = K / BKX;   // even (>= 16) for all launches here

  // prologue: tile0 (4 halves) + tile1 hA0,hB0; drain tile0 (leave 4 in flight)
  stA(0, 0, 0); stB(0, 0, 0); stA(0, 0, 1); stB(0, 0, 1);
  stA(1, 32768, 0); stB(1, 32768, 0);
  { asm volatile("s_waitcnt vmcnt(4)" ::: "memory"); }
  __builtin_amdgcn_s_barrier();

  // stage schedule (verified ledger r13):
  //   P1 hA1(T0+1) P2 hB1(T0+1) P3 hA0(T0+2) P4 hB0(T0+2)
  //   P5 hA1(T0+2) P6 hB1(T0+2) P7 hA0(T0+3) P8 hB0(T0+3)
#define STEP(STG) { \
    rdFA(0, 0); rdFB(0, 0, fbq0); stA(T0 + 1, 32768, 1);              /* P1 */ \
    VMCNT6; PH_BAR; MM16(0, 0, fbq0); PH_END; \
    rdFB(0, 1, fbq1); stB(T0 + 1, 32768, 1);                          /* P2 */ \
    PH_BAR; MM16(0, 1, fbq1); PH_END; \
    rdFA(0, 1); if (STG) stA(T0 + 2, 0, 0);                           /* P3 */ \
    PH_BAR; MM16(1, 0, fbq0); PH_END; \
    if (STG) stB(T0 + 2, 0, 0);                                       /* P4 */ \
    MM16(1, 1, fbq1); \
    if (STG) { VMCNT8 } else { VMCNT0 } \
    BARONLY; \
    rdFA(32768, 0); rdFB(32768, 0, fbq0); if (STG) stA(T0 + 2, 0, 1); /* P5 */ \
    VMCNT6; PH_BAR; MM16(0, 0, fbq0); PH_END; \
    rdFB(32768, 1, fbq1); if (STG) stB(T0 + 2, 0, 1);                 /* P6 */ \
    PH_BAR; MM16(0, 1, fbq1); PH_END; \
    rdFA(32768, 1); if (STG) stA(T0 + 3, 32768, 0);                   /* P7 */ \
    PH_BAR; MM16(1, 0, fbq0); PH_END; \
    if (STG) stB(T0 + 3, 32768, 0);                                   /* P8 */ \
    MM16(1, 1, fbq1); \
    if (STG) { VMCNT8 } \
    BARONLY; \
  }

  int T0 = 0;
  for (; T0 + 2 < nK; T0 += 2) STEP(1);
  STEP(0);
#undef STEP

  // ---- LDS-staged coalesced epilogue (r14, verified) ----
  __builtin_amdgcn_s_barrier();   // all waves done reading LDS (tail drained vmcnt0)
  bf16* ct = (bf16*)ldsbuf;   // [256][256] bf16 = 128KB
#pragma unroll
  for (int j = 0; j < 4; ++j) {
    const int lcol = wn * 64 + (j >> 1) * 32 + (j & 1) * 16 + lr;
    float bv = 0.f;
    if constexpr (EPI == 6) {
      const int gcol = colBase + lcol;
      const int c = gcol & 1023;
      const int cb = gcol >> 10;
      bv = (cb == 0 ? bias : (cb == 1 ? bias2 : bias3))[c];
    } else if constexpr (EPI == 3) {
      bv = bias[colBase + lcol];
    }
#pragma unroll
    for (int i = 0; i < 8; ++i) {
      const int lrow0 = wm * 128 + (i >> 2) * 64 + (i & 3) * 16 + g * 4;
#pragma unroll
      for (int rr2 = 0; rr2 < 4; ++rr2) {
        const int lrow = lrow0 + rr2;
        float v = acc[i][j][rr2];
        if constexpr (EPI == 5) v *= scale;
        else v += bv;
        if constexpr (EPI == 3) v = v > 0.f ? v : 0.f;
        ct[lrow * 256 + (lcol ^ (((lrow >> 2) & 3) << 4))] = (bf16)v;
      }
    }
  }
  __syncthreads();
  bf16* dstB; int ldst; long long colG;
  if constexpr (EPI == 6) {
    const int cb = colBase >> 10;
    dstB = (cb == 0 ? (bf16*)out : (cb == 1 ? (bf16*)out2 : (bf16*)out3));
    ldst = EMBED; colG = colBase & 1023;
  } else if constexpr (EPI == 5) {
    dstB = (bf16*)out + (long long)zb * sOz + (long long)kh * sOk;
    ldst = ldo; colG = colBase;
  } else {
    dstB = (bf16*)out; ldst = ldo; colG = colBase;
  }
  const int srow = tid >> 5, sc = tid & 31;
#pragma unroll
  for (int p = 0; p < 16; ++p) {
    const int row = p * 16 + srow;
    bf16x8 vrow = *(const bf16x8*)((const char*)ct + row * 512 + ((sc * 16) ^ (((row >> 2) & 3) << 5)));
    *(bf16x8*)(dstB + (long long)(rowBase + row) * ldst + colG + sc * 8) = vrow;
  }
}

// ---------------- row softmax: E bf16 [rows][SEQ] -> P bf16 ----------------
__global__ __launch_bounds__(256) void softmax_kernel(const bf16* __restrict__ E,
                                                      bf16* __restrict__ P) {
  const size_t row = blockIdx.x;
  const int t = threadIdx.x;
  bf16x8 ev = *(const bf16x8*)(E + row * SEQ + (size_t)t * 8);
  float e[8];
#pragma unroll
  for (int q = 0; q < 8; ++q) e[q] = (float)ev[q];
  float m = e[0];
#pragma unroll
  for (int q = 1; q < 8; ++q) m = fmaxf(m, e[q]);
#pragma unroll
  for (int o = 32; o; o >>= 1) m = fmaxf(m, __shfl_xor(m, o));
  __shared__ float red[8];
  const int w = t >> 6;
  if ((t & 63) == 0) red[w] = m;
  __syncthreads();
  m = fmaxf(fmaxf(red[0], red[1]), fmaxf(red[2], red[3]));
  float s = 0.f;
#pragma unroll
  for (int q = 0; q < 8; ++q) { e[q] = __expf(e[q] - m); s += e[q]; }
#pragma unroll
  for (int o = 32; o; o >>= 1) s += __shfl_xor(s, o);
  if ((t & 63) == 0) red[4 + w] = s;
  __syncthreads();
  s = red[4] + red[5] + red[6] + red[7];
  const float inv = 1.0f / s;
  bf16x8 pv;
#pragma unroll
  for (int q = 0; q < 8; ++q) pv[q] = (bf16)(e[q] * inv);
  *(bf16x8*)(P + row * SEQ + (size_t)t * 8) = pv;
}

// ---------------- LayerNorm: out = LN(Xb + X2b [+cb] + Rb) * g + b ----------------
__global__ __launch_bounds__(256) void ln_kernel(const bf16* __restrict__ Xb,
                                                 const bf16* __restrict__ X2b,
                                                 const bf16* __restrict__ Rb,
                                                 const float* __restrict__ cb,
                                                 const float* __restrict__ gm,
                                                 const float* __restrict__ bt,
                                                 float* __restrict__ of,
                                                 bf16* __restrict__ ob) {
  const size_t row = blockIdx.x;
  const int t = threadIdx.x;
  bf16x4 xv = *(const bf16x4*)(Xb + row * EMBED + (size_t)t * 4);
  bf16x4 rv = *(const bf16x4*)(Rb + row * EMBED + (size_t)t * 4);
  float4 v;
  v.x = (float)xv[0] + (float)rv[0];
  v.y = (float)xv[1] + (float)rv[1];
  v.z = (float)xv[2] + (float)rv[2];
  v.w = (float)xv[3] + (float)rv[3];
  if (X2b) {
    bf16x4 x2 = *(const bf16x4*)(X2b + row * EMBED + (size_t)t * 4);
    v.x += (float)x2[0]; v.y += (float)x2[1]; v.z += (float)x2[2]; v.w += (float)x2[3];
  }
  if (cb) {
    float4 c4 = ((const float4*)cb)[t];
    v.x += c4.x; v.y += c4.y; v.z += c4.z; v.w += c4.w;
  }
  float s  = v.x + v.y + v.z + v.w;
  float ss = v.x * v.x + v.y * v.y + v.z * v.z + v.w * v.w;
#pragma unroll
  for (int o = 32; o; o >>= 1) { s += __shfl_xor(s, o); ss += __shfl_xor(ss, o); }
  __shared__ float red[8];
  const int w = t >> 6;
  if ((t & 63) == 0) { red[w] = s; red[4 + w] = ss; }
  __syncthreads();
  s  = red[0] + red[1] + red[2] + red[3];
  ss = red[4] + red[5] + red[6] + red[7];
  const float mu  = s * (1.0f / EMBED);
  const float inv = rsqrtf(ss * (1.0f / EMBED) - mu * mu + 1e-5f);
  float4 gv = ((const float4*)gm)[t];
  float4 bv = ((const float4*)bt)[t];
  float4 o4;
  o4.x = (v.x - mu) * inv * gv.x + bv.x;
  o4.y = (v.y - mu) * inv * gv.y + bv.y;
  o4.z = (v.z - mu) * inv * gv.z + bv.z;
  o4.w = (v.w - mu) * inv * gv.w + bv.w;
  if (of) ((float4*)(of + row * EMBED))[t] = o4;
  if (ob) {
    bf16x4 p;
    p[0] = (bf16)o4.x; p[1] = (bf16)o4.y; p[2] = (bf16)o4.z; p[3] = (bf16)o4.w;
    *(bf16x4*)(ob + row * EMBED + (size_t)t * 4) = p;
  }
}

// ---------------- launch ----------------
extern "C" void kernel_launch(void* const* d_in, const int* in_sizes, int n_in,
                              void* d_out, int out_size, void* d_ws, size_t ws_size,
                              hipStream_t stream) {
  const float* x   = (const float*)d_in[0];
  const float* Wq  = (const float*)d_in[1];
  const float* bq  = (const float*)d_in[2];
  const float* Wk  = (const float*)d_in[3];
  const float* bk  = (const float*)d_in[4];
  const float* Wv  = (const float*)d_in[5];
  const float* bv  = (const float*)d_in[6];
  const float* W1  = (const float*)d_in[7];
  const float* b1  = (const float*)d_in[8];
  const float* W2  = (const float*)d_in[9];
  const float* b2  = (const float*)d_in[10];
  const float* g1  = (const float*)d_in[11];
  const float* be1 = (const float*)d_in[12];
  const float* g2  = (const float*)d_in[13];
  const float* be2 = (const float*)d_in[14];
  float* out = (float*)d_out;
  char* ws = (char*)d_ws;

  bf16*  hb   = (bf16*)(ws + OFF_HB);
  bf16*  xpeb = (bf16*)(ws + OFF_XPE_B);
  bf16*  Qb   = (bf16*)(ws + OFF_Q);
  bf16*  Kb   = (bf16*)(ws + OFF_K);
  bf16*  VT   = (bf16*)(ws + OFF_VT);
  bf16*  Vb   = (bf16*)(ws + OFF_ATTN);   // row-major V (dead after vtrans)
  bf16*  E    = (bf16*)(ws + OFF_E);      // 32MB bf16
  bf16*  P    = (bf16*)(ws + OFF_Q);      // reuse Q+K region after QK^T
  bf16*  pv0  = (bf16*)(ws + OFF_ATTN);   // PV part 0 (Vb dead)
  bf16*  pv1  = (bf16*)(ws + OFF_E);      // PV part 1 (E dead after softmax)
  bf16*  T1   = (bf16*)(ws + OFF_E);      // FF1 out (pv1 dead after LN1)
  bf16*  ff0  = (bf16*)(ws + OFF_ATTN);   // FF2 part 0 (pv0 dead)
  bf16*  ff1  = (bf16*)(ws + OFF_Q);      // FF2 part 1 (P dead)
  bf16*  WqkvT = (bf16*)(ws + OFF_WQKVT);
  bf16*  W1T  = (bf16*)(ws + OFF_W1T);
  bf16*  W2T  = (bf16*)(ws + OFF_W2T);

  const long long sOk_pv = ((long long)OFF_E - (long long)OFF_ATTN) / 2;   // pv1 - pv0
  const long long sOk_ff = ((long long)OFF_Q - (long long)OFF_ATTN) / 2;   // ff1 - ff0

  const dim3 tb(32, 8);
  transpose_kernel<<<dim3(EMBED / 32, EMBED / 32), tb, 0, stream>>>(Wq, WqkvT, EMBED, EMBED);
  transpose_kernel<<<dim3(EMBED / 32, EMBED / 32), tb, 0, stream>>>(Wk, WqkvT + (size_t)EMBED * EMBED, EMBED, EMBED);
  transpose_kernel<<<dim3(EMBED / 32, EMBED / 32), tb, 0, stream>>>(Wv, WqkvT + 2ull * EMBED * EMBED, EMBED, EMBED);
  transpose_kernel<<<dim3(FFDIM / 32, EMBED / 32), tb, 0, stream>>>(W1, W1T, EMBED, FFDIM);
  transpose_kernel<<<dim3(EMBED / 32, FFDIM / 32), tb, 0, stream>>>(W2, W2T, FFDIM, EMBED);

  pe_add_kernel<<<(SEQ * 512) / 256, 256, 0, stream>>>(x, xpeb);

  // fused QKV, all row-major (384 blocks)
  gemm8_kernel<6><<<dim3(3072 / BNX, MTOK / BMX, 1), 512, 0, stream>>>(
      xpeb, WqkvT, bq, Qb, EMBED, EMBED, EMBED, EMBED, 1,
      0, 0, 0, 0, 0, 0, 1.0f, bk, bv, Kb, Vb);

  // V -> VT (coalesced LDS transpose)
  vtrans_kernel<<<dim3(EMBED / 32, SEQ / 32, BATCH), tb, 0, stream>>>(Vb, VT);

  // QK^T: E = bf16(Q @ K^T / 32)  (256 blocks)
  gemm8_kernel<5><<<dim3(SEQ / BNX, SEQ / BMX, BATCH), 512, 0, stream>>>(
      Qb, Kb, nullptr, E, EMBED, EMBED, EMBED, SEQ, BATCH,
      (long long)SEQ * EMBED, (long long)SEQ * EMBED, (long long)SEQ * SEQ,
      0, 0, 0, 0.03125f, nullptr, nullptr, nullptr, nullptr);

  softmax_kernel<<<BATCH * SEQ, 256, 0, stream>>>(E, P);

  // PV split-K: K=2048 -> 2x1024, bf16 partials (256 blocks)
  gemm8_kernel<5><<<dim3(EMBED / BNX, SEQ / BMX, BATCH * 2), 512, 0, stream>>>(
      P, VT, nullptr, pv0, 1024, SEQ, SEQ, EMBED, BATCH,
      (long long)SEQ * SEQ, (long long)EMBED * SEQ, (long long)SEQ * EMBED,
      1024, 1024, sOk_pv,
      1.0f, nullptr, nullptr, nullptr, nullptr);

  // hb = bf16(LN(pv0 + pv1 + xpeb))
  ln_kernel<<<MTOK, 256, 0, stream>>>(pv0, pv1, xpeb, nullptr, g1, be1, nullptr, hb);

  // FF1: relu(hb @ W1 + b1)  (512 blocks)
  gemm8_kernel<3><<<dim3(FFDIM / BNX, MTOK / BMX, 1), 512, 0, stream>>>(
      hb, W1T, b1, T1, EMBED, EMBED, EMBED, FFDIM, 1,
      0, 0, 0, 0, 0, 0, 1.0f, nullptr, nullptr, nullptr, nullptr);

  // FF2 split-K: K=4096 -> 2x2048, bf16 partials (256 blocks); bias folded into LN2
  gemm8_kernel<5><<<dim3(EMBED / BNX, MTOK / BMX, 2), 512, 0, stream>>>(
      T1, W2T, nullptr, ff0, 2048, FFDIM, FFDIM, EMBED, 1,
      0, 0, 0,
      2048, 2048, sOk_ff,
      1.0f, nullptr, nullptr, nullptr, nullptr);

  // out = LN(ff0 + ff1 + b2 + hb)
  ln_kernel<<<MTOK, 256, 0, stream>>>(ff0, ff1, hb, b2, g2, be2, out, nullptr);
}

// Round 17
// 324.175 us; speedup vs baseline: 1.0264x; 1.0264x over previous
//
#include <hip/hip_runtime.h>
#include <hip/hip_bf16.h>
#include <cmath>
#include <cstdint>

typedef __bf16 bf16;
typedef __bf16 bf16x8 __attribute__((ext_vector_type(8)));
typedef __bf16 bf16x4 __attribute__((ext_vector_type(4)));
typedef float  f32x4  __attribute__((ext_vector_type(4)));

#define EMBED 1024
#define FFDIM 4096
#define BATCH 4
#define SEQ   2048
#define MTOK  (BATCH*SEQ)

// ---------------- workspace layout ----------------
static constexpr size_t OFF_HB    = 0;              // 16MB bf16 hb (LN1 w; FF1,LN2 r)
static constexpr size_t OFF_XPE_B = 32ull << 20;    // 16MB bf16 xpeb (PE w; QKV,LN1 r)
static constexpr size_t OFF_Q     = 48ull << 20;    // Qb 16MB; then P 32MB (48-80); then ff1 bf16
static constexpr size_t OFF_K     = 64ull << 20;
static constexpr size_t OFF_VT    = 80ull << 20;    // 16MB bf16 [4][1024][2048] — written directly by QKV
static constexpr size_t OFF_E     = 96ull << 20;    // E bf16 32MB; then pv1 bf16; then T1 bf16 64MB
static constexpr size_t OFF_ATTN  = 160ull << 20;   // pv0 bf16; then ff0 bf16
static constexpr size_t OFF_WQKVT = 224ull << 20;   // 6MB bf16 [3072][1024]
static constexpr size_t OFF_W1T   = 230ull << 20;   // 8MB
static constexpr size_t OFF_W2T   = 238ull << 20;   // 8MB

// ---------------- wait/barrier primitives (r16 bare set, verified) ----------------
#define VMCNT6 { asm volatile("s_waitcnt vmcnt(6)" ::: "memory"); }
#define VMCNT8 { asm volatile("s_waitcnt vmcnt(8)" ::: "memory"); }
#define VMCNT0 { asm volatile("s_waitcnt vmcnt(0)" ::: "memory"); }
#define PH_BAR  { __builtin_amdgcn_s_barrier(); }
#define BARONLY { __builtin_amdgcn_s_barrier(); }

__device__ __forceinline__ void gload_lds16(const void* g, void* l) {
  __builtin_amdgcn_global_load_lds((const __attribute__((address_space(1))) void*)g,
                                   (__attribute__((address_space(3))) void*)l, 16, 0, 0);
}

// ---------------- PE add: xb = bf16(x + pe) ----------------
__global__ __launch_bounds__(256) void pe_add_kernel(const float* __restrict__ x,
                                                     bf16* __restrict__ xb) {
  int idx  = blockIdx.x * 256 + threadIdx.x;
  int pair = idx & 511;
  int s    = idx >> 9;
  float div = __expf((float)(2 * pair) * (-9.210340371976184f / (float)EMBED));
  float ang = (float)s * div;
  float sv = sinf(ang), cv = cosf(ang);
#pragma unroll
  for (int b = 0; b < BATCH; ++b) {
    size_t base = ((size_t)(b * SEQ + s)) * EMBED + (size_t)pair * 2;
    xb[base]     = (bf16)(x[base] + sv);
    xb[base + 1] = (bf16)(x[base + 1] + cv);
  }
}

// ---------------- weight transpose fp32[K][N] -> bf16[N][K] ----------------
__global__ __launch_bounds__(256) void transpose_kernel(const float* __restrict__ W,
                                                        bf16* __restrict__ Wt,
                                                        int K, int N) {
  __shared__ float tile[32][33];
  int nb = blockIdx.x * 32, kb = blockIdx.y * 32;
  int tx = threadIdx.x, ty = threadIdx.y;   // 32x8
#pragma unroll
  for (int i = 0; i < 32; i += 8)
    tile[ty + i][tx] = W[(size_t)(kb + ty + i) * N + nb + tx];
  __syncthreads();
#pragma unroll
  for (int i = 0; i < 32; i += 8)
    Wt[(size_t)(nb + ty + i) * K + kb + tx] = (bf16)tile[tx][ty + i];
}

// ---------------- gemm8: 256x256 tile, 8 waves (2Mx4N), 8-phase counted-vmcnt ----------------
// r14 LDS-staged epilogue; r17: QKV V-blocks write the ct tile d-major so the
// coalesced store emits VT directly (vtrans kernel eliminated).
// EPI 5: bf16 *scale (+batch +split-K)  EPI 3: bf16 +bias relu  EPI 6: fused QKV
#define BMX 256
#define BNX 256
#define BKX 64

#define MM16(QR, QC, FB) { \
  __builtin_amdgcn_s_setprio(1); \
  _Pragma("unroll") for (int kk = 0; kk < 2; ++kk) \
  _Pragma("unroll") for (int i2 = 0; i2 < 4; ++i2) \
  _Pragma("unroll") for (int j2 = 0; j2 < 2; ++j2) \
    acc[(QR)*4 + i2][(QC)*2 + j2] = __builtin_amdgcn_mfma_f32_16x16x32_bf16( \
        fa[kk][i2], FB[kk][j2], acc[(QR)*4 + i2][(QC)*2 + j2], 0, 0, 0); \
  __builtin_amdgcn_s_setprio(0); }

template <int EPI>
__global__ __launch_bounds__(512, 2) void gemm8_kernel(
    const bf16* __restrict__ A, const bf16* __restrict__ B,
    const float* __restrict__ bias, void* __restrict__ out,
    int K, int lda, int ldb, int ldo, int NB,
    long long sAz, long long sBz, long long sOz,
    long long sAk, long long sBk, long long sOk,
    float scale,
    const float* bias2, const float* bias3, void* out2, void* out3) {
  __shared__ __align__(16) char ldsbuf[131072];
  char* const ldsA = ldsbuf;            // 2buf x 32KB
  char* const ldsB = ldsbuf + 65536;    // 2buf x 32KB

  // T1: bijective XCD-chunked swizzle + grouped raster (G=8)
  const int gx = gridDim.x, gy = gridDim.y;
  int id = blockIdx.x + gx * (blockIdx.y + gy * blockIdx.z);
  const int nwg = gx * gy * gridDim.z;
  const int qd = nwg >> 3, rm = nwg & 7;
  const int xcd = id & 7, pos = id >> 3;
  const int lid = (xcd < rm ? xcd * (qd + 1) : rm * (qd + 1) + (xcd - rm) * qd) + pos;
  const int per = gx * gy;
  const int tz = lid / per;
  const int s2 = lid - tz * per;
  const int G = 8;
  const int ngrp = G * gy;
  const int grp = s2 / ngrp;
  const int within = s2 - grp * ngrp;
  const int gwf = gx - grp * G;
  const int gw = gwf < G ? gwf : G;
  const int tx = grp * G + within % gw;
  const int ty = within / gw;

  const int zb = tz % NB;
  const int kh = tz / NB;
  A += (long long)zb * sAz + (long long)kh * sAk;
  B += (long long)zb * sBz + (long long)kh * sBk;

  const int tid  = threadIdx.x;
  const int wave = tid >> 6;
  const int lane = tid & 63;
  const int wm = wave >> 2, wn = wave & 3;   // 2M x 4N
  const int rowBase = ty * BMX;
  const int colBase = tx * BNX;
  const int lr = lane & 15;
  const int g  = lane >> 4;
  const int lx = lr & 7;

  // staging: thread t -> rr = t>>3, slot (t&7)^(rr&7) (src pre-swizzled, rule 21)
  const int rr = tid >> 3;
  const int slot = (tid & 7) ^ (rr & 7);
  const bf16* Abase = A + (long long)(rowBase + rr) * lda + slot * 8;
  const bf16* Bb0 = B + (long long)(colBase + (rr & 31) + ((rr >> 5)) * 64) * ldb + slot * 8;
  const bf16* Bb1 = B + (long long)(colBase + (rr & 31) + (2 + (rr >> 5)) * 64) * ldb + slot * 8;

  auto stA = [&](int T, int bufOff, int qr) {
    char* dst = ldsA + bufOff + qr * 16384 + wave * 1024;
    const bf16* s = Abase + (long long)(qr * 64) * lda + (long long)T * BKX;
    gload_lds16(s, dst);
    gload_lds16(s + (long long)128 * lda, dst + 8192);
  };
  auto stB = [&](int T, int bufOff, int qc) {
    char* dst = ldsB + bufOff + qc * 16384 + wave * 1024;
    const long long off = (long long)(qc * 32) * ldb + (long long)T * BKX;
    gload_lds16(Bb0 + off, dst);
    gload_lds16(Bb1 + off, dst + 8192);
  };

  bf16x8 fa[2][4], fbq0[2][2], fbq1[2][2];
  auto rdFA = [&](int bufOff, int qr) {
    const char* base = ldsA + bufOff + qr * 16384 + wm * 8192;
#pragma unroll
    for (int kk = 0; kk < 2; ++kk) {
      const int sw = ((kk * 4 + g) ^ lx) << 4;
#pragma unroll
      for (int i2 = 0; i2 < 4; ++i2)
        fa[kk][i2] = *(const bf16x8*)(base + (i2 * 16 + lr) * 128 + sw);
    }
  };
  auto rdFB = [&](int bufOff, int qc, bf16x8 fb[2][2]) {
    const char* base = ldsB + bufOff + qc * 16384 + wn * 4096;
#pragma unroll
    for (int kk = 0; kk < 2; ++kk) {
      const int sw = ((kk * 4 + g) ^ lx) << 4;
#pragma unroll
      for (int j2 = 0; j2 < 2; ++j2)
        fb[kk][j2] = *(const bf16x8*)(base + (j2 * 16 + lr) * 128 + sw);
    }
  };

  const f32x4 zero4 = {0.f, 0.f, 0.f, 0.f};
  f32x4 acc[8][4];
#pragma unroll
  for (int i = 0; i < 8; ++i)
#pragma unroll
    for (int j = 0; j < 4; ++j) acc[i][j] = zero4;

  const int nK = K / BKX;   // even (>= 16) for all launches here

  // prologue: tile0 (4 halves) + tile1 hA0,hB0; drain tile0 (leave 4 in flight)
  stA(0, 0, 0); stB(0, 0, 0); stA(0, 0, 1); stB(0, 0, 1);
  stA(1, 32768, 0); stB(1, 32768, 0);
  { asm volatile("s_waitcnt vmcnt(4)" ::: "memory"); }
  __builtin_amdgcn_s_barrier();

  // stage schedule (verified ledger r13):
  //   P1 hA1(T0+1) P2 hB1(T0+1) P3 hA0(T0+2) P4 hB0(T0+2)
  //   P5 hA1(T0+2) P6 hB1(T0+2) P7 hA0(T0+3) P8 hB0(T0+3)
#define STEP(STG) { \
    rdFA(0, 0); rdFB(0, 0, fbq0); stA(T0 + 1, 32768, 1);              /* P1 */ \
    VMCNT6; PH_BAR; MM16(0, 0, fbq0); \
    rdFB(0, 1, fbq1); stB(T0 + 1, 32768, 1);                          /* P2 */ \
    PH_BAR; MM16(0, 1, fbq1); \
    rdFA(0, 1); if (STG) stA(T0 + 2, 0, 0);                           /* P3 */ \
    PH_BAR; MM16(1, 0, fbq0); \
    if (STG) stB(T0 + 2, 0, 0);                                       /* P4 */ \
    MM16(1, 1, fbq1); \
    if (STG) { VMCNT8 } else { VMCNT0 } \
    BARONLY; \
    rdFA(32768, 0); rdFB(32768, 0, fbq0); if (STG) stA(T0 + 2, 0, 1); /* P5 */ \
    VMCNT6; PH_BAR; MM16(0, 0, fbq0); \
    rdFB(32768, 1, fbq1); if (STG) stB(T0 + 2, 0, 1);                 /* P6 */ \
    PH_BAR; MM16(0, 1, fbq1); \
    rdFA(32768, 1); if (STG) stA(T0 + 3, 32768, 0);                   /* P7 */ \
    PH_BAR; MM16(1, 0, fbq0); \
    if (STG) stB(T0 + 3, 32768, 0);                                   /* P8 */ \
    MM16(1, 1, fbq1); \
    if (STG) { VMCNT8 } \
    BARONLY; \
  }

  int T0 = 0;
  for (; T0 + 2 < nK; T0 += 2) STEP(1);
  STEP(0);
#undef STEP

  // ---- LDS-staged coalesced epilogue ----
  __builtin_amdgcn_s_barrier();   // all waves past K-loop; loads drained (tail vmcnt0)
  bf16* ct = (bf16*)ldsbuf;       // [256][256] bf16 = 128KB
  const bool vblk = (EPI == 6) && ((colBase >> 10) == 2);
#pragma unroll
  for (int j = 0; j < 4; ++j) {
    const int lcol = wn * 64 + (j >> 1) * 32 + (j & 1) * 16 + lr;
    float bv = 0.f;
    if constexpr (EPI == 6) {
      const int gcol = colBase + lcol;
      const int c = gcol & 1023;
      const int cb = gcol >> 10;
      bv = (cb == 0 ? bias : (cb == 1 ? bias2 : bias3))[c];
    } else if constexpr (EPI == 3) {
      bv = bias[colBase + lcol];
    }
#pragma unroll
    for (int i = 0; i < 8; ++i) {
      const int lrow0 = wm * 128 + (i >> 2) * 64 + (i & 3) * 16 + g * 4;
      if (vblk) {
        // d-major tile: ct[d][s ^ f(d)], f(d) = ((d>>2)&3)<<4 — 4-contiguous s preserved
        bf16x4 pv;
#pragma unroll
        for (int rr2 = 0; rr2 < 4; ++rr2) pv[rr2] = (bf16)(acc[i][j][rr2] + bv);
        *(bf16x4*)&ct[lcol * 256 + (lrow0 ^ (((lcol >> 2) & 3) << 4))] = pv;
      } else {
#pragma unroll
        for (int rr2 = 0; rr2 < 4; ++rr2) {
          const int lrow = lrow0 + rr2;
          float v = acc[i][j][rr2];
          if constexpr (EPI == 5) v *= scale;
          else v += bv;
          if constexpr (EPI == 3) v = v > 0.f ? v : 0.f;
          ct[lrow * 256 + (lcol ^ (((lrow >> 2) & 3) << 4))] = (bf16)v;
        }
      }
    }
  }
  __syncthreads();
  // coalesced store: 16 passes, each instr reads a full swizzled ct row (512B x2)
  bf16* dstB; int ldst; long long rowG, colG;
  if constexpr (EPI == 6) {
    const int cb = colBase >> 10;
    if (cb == 2) {
      // VT[b][d][s]: tile rows are d, cols are s
      dstB = (bf16*)out3 + (long long)(rowBase >> 11) * EMBED * SEQ;
      ldst = SEQ; rowG = colBase & 1023; colG = rowBase & (SEQ - 1);
    } else {
      dstB = (cb == 0 ? (bf16*)out : (bf16*)out2);
      ldst = EMBED; rowG = rowBase; colG = colBase & 1023;
    }
  } else if constexpr (EPI == 5) {
    dstB = (bf16*)out + (long long)zb * sOz + (long long)kh * sOk;
    ldst = ldo; rowG = rowBase; colG = colBase;
  } else {
    dstB = (bf16*)out; ldst = ldo; rowG = rowBase; colG = colBase;
  }
  const int srow = tid >> 5, sc = tid & 31;
#pragma unroll
  for (int p = 0; p < 16; ++p) {
    const int row = p * 16 + srow;
    bf16x8 vrow = *(const bf16x8*)((const char*)ct + row * 512 + ((sc * 16) ^ (((row >> 2) & 3) << 5)));
    *(bf16x8*)(dstB + (long long)(rowG + row) * ldst + colG + sc * 8) = vrow;
  }
}

// ---------------- row softmax: E bf16 [rows][SEQ] -> P bf16 ----------------
__global__ __launch_bounds__(256) void softmax_kernel(const bf16* __restrict__ E,
                                                      bf16* __restrict__ P) {
  const size_t row = blockIdx.x;
  const int t = threadIdx.x;
  bf16x8 ev = *(const bf16x8*)(E + row * SEQ + (size_t)t * 8);
  float e[8];
#pragma unroll
  for (int q = 0; q < 8; ++q) e[q] = (float)ev[q];
  float m = e[0];
#pragma unroll
  for (int q = 1; q < 8; ++q) m = fmaxf(m, e[q]);
#pragma unroll
  for (int o = 32; o; o >>= 1) m = fmaxf(m, __shfl_xor(m, o));
  __shared__ float red[8];
  const int w = t >> 6;
  if ((t & 63) == 0) red[w] = m;
  __syncthreads();
  m = fmaxf(fmaxf(red[0], red[1]), fmaxf(red[2], red[3]));
  float s = 0.f;
#pragma unroll
  for (int q = 0; q < 8; ++q) { e[q] = __expf(e[q] - m); s += e[q]; }
#pragma unroll
  for (int o = 32; o; o >>= 1) s += __shfl_xor(s, o);
  if ((t & 63) == 0) red[4 + w] = s;
  __syncthreads();
  s = red[4] + red[5] + red[6] + red[7];
  const float inv = 1.0f / s;
  bf16x8 pv;
#pragma unroll
  for (int q = 0; q < 8; ++q) pv[q] = (bf16)(e[q] * inv);
  *(bf16x8*)(P + row * SEQ + (size_t)t * 8) = pv;
}

// ---------------- LayerNorm: out = LN(Xb + X2b [+cb] + Rb) * g + b ----------------
__global__ __launch_bounds__(256) void ln_kernel(const bf16* __restrict__ Xb,
                                                 const bf16* __restrict__ X2b,
                                                 const bf16* __restrict__ Rb,
                                                 const float* __restrict__ cb,
                                                 const float* __restrict__ gm,
                                                 const float* __restrict__ bt,
                                                 float* __restrict__ of,
                                                 bf16* __restrict__ ob) {
  const size_t row = blockIdx.x;
  const int t = threadIdx.x;
  bf16x4 xv = *(const bf16x4*)(Xb + row * EMBED + (size_t)t * 4);
  bf16x4 rv = *(const bf16x4*)(Rb + row * EMBED + (size_t)t * 4);
  float4 v;
  v.x = (float)xv[0] + (float)rv[0];
  v.y = (float)xv[1] + (float)rv[1];
  v.z = (float)xv[2] + (float)rv[2];
  v.w = (float)xv[3] + (float)rv[3];
  if (X2b) {
    bf16x4 x2 = *(const bf16x4*)(X2b + row * EMBED + (size_t)t * 4);
    v.x += (float)x2[0]; v.y += (float)x2[1]; v.z += (float)x2[2]; v.w += (float)x2[3];
  }
  if (cb) {
    float4 c4 = ((const float4*)cb)[t];
    v.x += c4.x; v.y += c4.y; v.z += c4.z; v.w += c4.w;
  }
  float s  = v.x + v.y + v.z + v.w;
  float ss = v.x * v.x + v.y * v.y + v.z * v.z + v.w * v.w;
#pragma unroll
  for (int o = 32; o; o >>= 1) { s += __shfl_xor(s, o); ss += __shfl_xor(ss, o); }
  __shared__ float red[8];
  const int w = t >> 6;
  if ((t & 63) == 0) { red[w] = s; red[4 + w] = ss; }
  __syncthreads();
  s  = red[0] + red[1] + red[2] + red[3];
  ss = red[4] + red[5] + red[6] + red[7];
  const float mu  = s * (1.0f / EMBED);
  const float inv = rsqrtf(ss * (1.0f / EMBED) - mu * mu + 1e-5f);
  float4 gv = ((const float4*)gm)[t];
  float4 bv = ((const float4*)bt)[t];
  float4 o4;
  o4.x = (v.x - mu) * inv * gv.x + bv.x;
  o4.y = (v.y - mu) * inv * gv.y + bv.y;
  o4.z = (v.z - mu) * inv * gv.z + bv.z;
  o4.w = (v.w - mu) * inv * gv.w + bv.w;
  if (of) ((float4*)(of + row * EMBED))[t] = o4;
  if (ob) {
    bf16x4 p;
    p[0] = (bf16)o4.x; p[1] = (bf16)o4.y; p[2] = (bf16)o4.z; p[3] = (bf16)o4.w;
    *(bf16x4*)(ob + row * EMBED + (size_t)t * 4) = p;
  }
}

// ---------------- launch ----------------
extern "C" void kernel_launch(void* const* d_in, const int* in_sizes, int n_in,
                              void* d_out, int out_size, void* d_ws, size_t ws_size,
                              hipStream_t stream) {
  const float* x   = (const float*)d_in[0];
  const float* Wq  = (const float*)d_in[1];
  const float* bq  = (const float*)d_in[2];
  const float* Wk  = (const float*)d_in[3];
  const float* bk  = (const float*)d_in[4];
  const float* Wv  = (const float*)d_in[5];
  const float* bv  = (const float*)d_in[6];
  const float* W1  = (const float*)d_in[7];
  const float* b1  = (const float*)d_in[8];
  const float* W2  = (const float*)d_in[9];
  const float* b2  = (const float*)d_in[10];
  const float* g1  = (const float*)d_in[11];
  const float* be1 = (const float*)d_in[12];
  const float* g2  = (const float*)d_in[13];
  const float* be2 = (const float*)d_in[14];
  float* out = (float*)d_out;
  char* ws = (char*)d_ws;

  bf16*  hb   = (bf16*)(ws + OFF_HB);
  bf16*  xpeb = (bf16*)(ws + OFF_XPE_B);
  bf16*  Qb   = (bf16*)(ws + OFF_Q);
  bf16*  Kb   = (bf16*)(ws + OFF_K);
  bf16*  VT   = (bf16*)(ws + OFF_VT);
  bf16*  E    = (bf16*)(ws + OFF_E);      // 32MB bf16
  bf16*  P    = (bf16*)(ws + OFF_Q);      // reuse Q+K region after QK^T
  bf16*  pv0  = (bf16*)(ws + OFF_ATTN);   // PV part 0
  bf16*  pv1  = (bf16*)(ws + OFF_E);      // PV part 1 (E dead after softmax)
  bf16*  T1   = (bf16*)(ws + OFF_E);      // FF1 out (pv1 dead after LN1)
  bf16*  ff0  = (bf16*)(ws + OFF_ATTN);   // FF2 part 0 (pv0 dead)
  bf16*  ff1  = (bf16*)(ws + OFF_Q);      // FF2 part 1 (P dead)
  bf16*  WqkvT = (bf16*)(ws + OFF_WQKVT);
  bf16*  W1T  = (bf16*)(ws + OFF_W1T);
  bf16*  W2T  = (bf16*)(ws + OFF_W2T);

  const long long sOk_pv = ((long long)OFF_E - (long long)OFF_ATTN) / 2;   // pv1 - pv0
  const long long sOk_ff = ((long long)OFF_Q - (long long)OFF_ATTN) / 2;   // ff1 - ff0

  const dim3 tb(32, 8);
  transpose_kernel<<<dim3(EMBED / 32, EMBED / 32), tb, 0, stream>>>(Wq, WqkvT, EMBED, EMBED);
  transpose_kernel<<<dim3(EMBED / 32, EMBED / 32), tb, 0, stream>>>(Wk, WqkvT + (size_t)EMBED * EMBED, EMBED, EMBED);
  transpose_kernel<<<dim3(EMBED / 32, EMBED / 32), tb, 0, stream>>>(Wv, WqkvT + 2ull * EMBED * EMBED, EMBED, EMBED);
  transpose_kernel<<<dim3(FFDIM / 32, EMBED / 32), tb, 0, stream>>>(W1, W1T, EMBED, FFDIM);
  transpose_kernel<<<dim3(EMBED / 32, FFDIM / 32), tb, 0, stream>>>(W2, W2T, FFDIM, EMBED);

  pe_add_kernel<<<(SEQ * 512) / 256, 256, 0, stream>>>(x, xpeb);

  // fused QKV: Q,K row-major; V written directly as VT (384 blocks)
  gemm8_kernel<6><<<dim3(3072 / BNX, MTOK / BMX, 1), 512, 0, stream>>>(
      xpeb, WqkvT, bq, Qb, EMBED, EMBED, EMBED, EMBED, 1,
      0, 0, 0, 0, 0, 0, 1.0f, bk, bv, Kb, VT);

  // QK^T: E = bf16(Q @ K^T / 32)  (256 blocks)
  gemm8_kernel<5><<<dim3(SEQ / BNX, SEQ / BMX, BATCH), 512, 0, stream>>>(
      Qb, Kb, nullptr, E, EMBED, EMBED, EMBED, SEQ, BATCH,
      (long long)SEQ * EMBED, (long long)SEQ * EMBED, (long long)SEQ * SEQ,
      0, 0, 0, 0.03125f, nullptr, nullptr, nullptr, nullptr);

  softmax_kernel<<<BATCH * SEQ, 256, 0, stream>>>(E, P);

  // PV split-K: K=2048 -> 2x1024, bf16 partials (256 blocks)
  gemm8_kernel<5><<<dim3(EMBED / BNX, SEQ / BMX, BATCH * 2), 512, 0, stream>>>(
      P, VT, nullptr, pv0, 1024, SEQ, SEQ, EMBED, BATCH,
      (long long)SEQ * SEQ, (long long)EMBED * SEQ, (long long)SEQ * EMBED,
      1024, 1024, sOk_pv,
      1.0f, nullptr, nullptr, nullptr, nullptr);

  // hb = bf16(LN(pv0 + pv1 + xpeb))
  ln_kernel<<<MTOK, 256, 0, stream>>>(pv0, pv1, xpeb, nullptr, g1, be1, nullptr, hb);

  // FF1: relu(hb @ W1 + b1)  (512 blocks)
  gemm8_kernel<3><<<dim3(FFDIM / BNX, MTOK / BMX, 1), 512, 0, stream>>>(
      hb, W1T, b1, T1, EMBED, EMBED, EMBED, FFDIM, 1,
      0, 0, 0, 0, 0, 0, 1.0f, nullptr, nullptr, nullptr, nullptr);

  // FF2 split-K: K=4096 -> 2x2048, bf16 partials (256 blocks); bias folded into LN2
  gemm8_kernel<5><<<dim3(EMBED / BNX, MTOK / BMX, 2), 512, 0, stream>>>(
      T1, W2T, nullptr, ff0, 2048, FFDIM, FFDIM, EMBED, 1,
      0, 0, 0,
      2048, 2048, sOk_ff,
      1.0f, nullptr, nullptr, nullptr, nullptr);

  // out = LN(ff0 + ff1 + b2 + hb)
  ln_kernel<<<MTOK, 256, 0, stream>>>(ff0, ff1, hb, b2, g2, be2, out, nullptr);
}

// Round 18
// 320.956 us; speedup vs baseline: 1.0366x; 1.0100x over previous
//
#include <hip/hip_runtime.h>
#include <hip/hip_bf16.h>
#include <cmath>
#include <cstdint>

typedef __bf16 bf16;
typedef __bf16 bf16x8 __attribute__((ext_vector_type(8)));
typedef __bf16 bf16x4 __attribute__((ext_vector_type(4)));
typedef float  f32x4  __attribute__((ext_vector_type(4)));

#define EMBED 1024
#define FFDIM 4096
#define BATCH 4
#define SEQ   2048
#define MTOK  (BATCH*SEQ)

// ---------------- workspace layout ----------------
static constexpr size_t OFF_HB    = 0;              // 16MB bf16 hb (LN1 w; FF1,LN2 r)
static constexpr size_t OFF_XPE_B = 32ull << 20;    // 16MB bf16 xpeb (PE w; QKV,LN1 r)
static constexpr size_t OFF_Q     = 48ull << 20;    // Qb 16MB; later ff1 bf16 (Qb dead after QK^T)
static constexpr size_t OFF_K     = 64ull << 20;
static constexpr size_t OFF_VT    = 80ull << 20;    // 16MB bf16 [4][1024][2048] — written directly by QKV
static constexpr size_t OFF_E     = 96ull << 20;    // Eexp bf16 32MB (96-128); later T1 bf16 64MB (96-160)
static constexpr size_t OFF_PV0   = 160ull << 20;   // pv0 bf16 16MB; later ff0 bf16
static constexpr size_t OFF_PV1   = 176ull << 20;   // pv1 bf16 16MB (must not alias Eexp while PV runs)
static constexpr size_t OFF_RS    = 192ull << 20;   // row-sum partials f32 [4][8][2048] = 256KB
static constexpr size_t OFF_LINV  = 200ull << 20;   // 1/rowsum f32 [4][2048] = 32KB
static constexpr size_t OFF_WQKVT = 224ull << 20;   // 6MB bf16 [3072][1024]
static constexpr size_t OFF_W1T   = 230ull << 20;   // 8MB
static constexpr size_t OFF_W2T   = 238ull << 20;   // 8MB

// ---------------- wait/barrier primitives (r16 bare set, verified) ----------------
#define VMCNT6 { asm volatile("s_waitcnt vmcnt(6)" ::: "memory"); }
#define VMCNT8 { asm volatile("s_waitcnt vmcnt(8)" ::: "memory"); }
#define VMCNT0 { asm volatile("s_waitcnt vmcnt(0)" ::: "memory"); }
#define PH_BAR  { __builtin_amdgcn_s_barrier(); }
#define BARONLY { __builtin_amdgcn_s_barrier(); }

__device__ __forceinline__ void gload_lds16(const void* g, void* l) {
  __builtin_amdgcn_global_load_lds((const __attribute__((address_space(1))) void*)g,
                                   (__attribute__((address_space(3))) void*)l, 16, 0, 0);
}

// ---------------- PE add: xb = bf16(x + pe) ----------------
__global__ __launch_bounds__(256) void pe_add_kernel(const float* __restrict__ x,
                                                     bf16* __restrict__ xb) {
  int idx  = blockIdx.x * 256 + threadIdx.x;
  int pair = idx & 511;
  int s    = idx >> 9;
  float div = __expf((float)(2 * pair) * (-9.210340371976184f / (float)EMBED));
  float ang = (float)s * div;
  float sv = sinf(ang), cv = cosf(ang);
#pragma unroll
  for (int b = 0; b < BATCH; ++b) {
    size_t base = ((size_t)(b * SEQ + s)) * EMBED + (size_t)pair * 2;
    xb[base]     = (bf16)(x[base] + sv);
    xb[base + 1] = (bf16)(x[base + 1] + cv);
  }
}

// ---------------- weight transpose fp32[K][N] -> bf16[N][K] ----------------
__global__ __launch_bounds__(256) void transpose_kernel(const float* __restrict__ W,
                                                        bf16* __restrict__ Wt,
                                                        int K, int N) {
  __shared__ float tile[32][33];
  int nb = blockIdx.x * 32, kb = blockIdx.y * 32;
  int tx = threadIdx.x, ty = threadIdx.y;   // 32x8
#pragma unroll
  for (int i = 0; i < 32; i += 8)
    tile[ty + i][tx] = W[(size_t)(kb + ty + i) * N + nb + tx];
  __syncthreads();
#pragma unroll
  for (int i = 0; i < 32; i += 8)
    Wt[(size_t)(nb + ty + i) * K + kb + tx] = (bf16)tile[tx][ty + i];
}

// ---------------- rowsum reduce: linv[b][row] = 1 / sum_cb rs[b][cb][row] ----------------
__global__ __launch_bounds__(256) void rowsum_inv_kernel(const float* __restrict__ rs,
                                                         float* __restrict__ linv) {
  const int idx = blockIdx.x * 256 + threadIdx.x;   // 0..8191
  const int b = idx >> 11, row = idx & 2047;
  const float* p = rs + ((long long)b * 8) * 2048 + row;
  float s = 0.f;
#pragma unroll
  for (int cb = 0; cb < 8; ++cb) s += p[cb * 2048];
  linv[idx] = 1.0f / s;
}

// ---------------- gemm8: 256x256 tile, 8 waves (2Mx4N), 8-phase counted-vmcnt ----------------
// EPI 3: bf16 +bias relu (FF1)     EPI 5: bf16 *scale (+batch +split-K) (FF2)
// EPI 6: fused QKV (Q,K row-major; V written d-major -> VT directly)
// EPI 8: QK^T: bf16 exp(acc*scale), + per-(batch,colblock,row) expsum partials -> out2
// EPI 9: PV:   bf16 acc * linv[batch*2048+row]  (linv passed via bias)
#define BMX 256
#define BNX 256
#define BKX 64

#define MM16(QR, QC, FB) { \
  __builtin_amdgcn_s_setprio(1); \
  _Pragma("unroll") for (int kk = 0; kk < 2; ++kk) \
  _Pragma("unroll") for (int i2 = 0; i2 < 4; ++i2) \
  _Pragma("unroll") for (int j2 = 0; j2 < 2; ++j2) \
    acc[(QR)*4 + i2][(QC)*2 + j2] = __builtin_amdgcn_mfma_f32_16x16x32_bf16( \
        fa[kk][i2], FB[kk][j2], acc[(QR)*4 + i2][(QC)*2 + j2], 0, 0, 0); \
  __builtin_amdgcn_s_setprio(0); }

template <int EPI>
__global__ __launch_bounds__(512, 2) void gemm8_kernel(
    const bf16* __restrict__ A, const bf16* __restrict__ B,
    const float* __restrict__ bias, void* __restrict__ out,
    int K, int lda, int ldb, int ldo, int NB,
    long long sAz, long long sBz, long long sOz,
    long long sAk, long long sBk, long long sOk,
    float scale,
    const float* bias2, const float* bias3, void* out2, void* out3) {
  __shared__ __align__(16) char ldsbuf[131072];
  char* const ldsA = ldsbuf;            // 2buf x 32KB
  char* const ldsB = ldsbuf + 65536;    // 2buf x 32KB

  // T1: bijective XCD-chunked swizzle + grouped raster (G=8)
  const int gx = gridDim.x, gy = gridDim.y;
  int id = blockIdx.x + gx * (blockIdx.y + gy * blockIdx.z);
  const int nwg = gx * gy * gridDim.z;
  const int qd = nwg >> 3, rm = nwg & 7;
  const int xcd = id & 7, pos = id >> 3;
  const int lid = (xcd < rm ? xcd * (qd + 1) : rm * (qd + 1) + (xcd - rm) * qd) + pos;
  const int per = gx * gy;
  const int tz = lid / per;
  const int s2 = lid - tz * per;
  const int G = 8;
  const int ngrp = G * gy;
  const int grp = s2 / ngrp;
  const int within = s2 - grp * ngrp;
  const int gwf = gx - grp * G;
  const int gw = gwf < G ? gwf : G;
  const int tx = grp * G + within % gw;
  const int ty = within / gw;

  const int zb = tz % NB;
  const int kh = tz / NB;
  A += (long long)zb * sAz + (long long)kh * sAk;
  B += (long long)zb * sBz + (long long)kh * sBk;

  const int tid  = threadIdx.x;
  const int wave = tid >> 6;
  const int lane = tid & 63;
  const int wm = wave >> 2, wn = wave & 3;   // 2M x 4N
  const int rowBase = ty * BMX;
  const int colBase = tx * BNX;
  const int lr = lane & 15;
  const int g  = lane >> 4;
  const int lx = lr & 7;

  // staging: thread t -> rr = t>>3, slot (t&7)^(rr&7) (src pre-swizzled, rule 21)
  const int rr = tid >> 3;
  const int slot = (tid & 7) ^ (rr & 7);
  const bf16* Abase = A + (long long)(rowBase + rr) * lda + slot * 8;
  const bf16* Bb0 = B + (long long)(colBase + (rr & 31) + ((rr >> 5)) * 64) * ldb + slot * 8;
  const bf16* Bb1 = B + (long long)(colBase + (rr & 31) + (2 + (rr >> 5)) * 64) * ldb + slot * 8;

  auto stA = [&](int T, int bufOff, int qr) {
    char* dst = ldsA + bufOff + qr * 16384 + wave * 1024;
    const bf16* s = Abase + (long long)(qr * 64) * lda + (long long)T * BKX;
    gload_lds16(s, dst);
    gload_lds16(s + (long long)128 * lda, dst + 8192);
  };
  auto stB = [&](int T, int bufOff, int qc) {
    char* dst = ldsB + bufOff + qc * 16384 + wave * 1024;
    const long long off = (long long)(qc * 32) * ldb + (long long)T * BKX;
    gload_lds16(Bb0 + off, dst);
    gload_lds16(Bb1 + off, dst + 8192);
  };

  bf16x8 fa[2][4], fbq0[2][2], fbq1[2][2];
  auto rdFA = [&](int bufOff, int qr) {
    const char* base = ldsA + bufOff + qr * 16384 + wm * 8192;
#pragma unroll
    for (int kk = 0; kk < 2; ++kk) {
      const int sw = ((kk * 4 + g) ^ lx) << 4;
#pragma unroll
      for (int i2 = 0; i2 < 4; ++i2)
        fa[kk][i2] = *(const bf16x8*)(base + (i2 * 16 + lr) * 128 + sw);
    }
  };
  auto rdFB = [&](int bufOff, int qc, bf16x8 fb[2][2]) {
    const char* base = ldsB + bufOff + qc * 16384 + wn * 4096;
#pragma unroll
    for (int kk = 0; kk < 2; ++kk) {
      const int sw = ((kk * 4 + g) ^ lx) << 4;
#pragma unroll
      for (int j2 = 0; j2 < 2; ++j2)
        fb[kk][j2] = *(const bf16x8*)(base + (j2 * 16 + lr) * 128 + sw);
    }
  };

  const f32x4 zero4 = {0.f, 0.f, 0.f, 0.f};
  f32x4 acc[8][4];
#pragma unroll
  for (int i = 0; i < 8; ++i)
#pragma unroll
    for (int j = 0; j < 4; ++j) acc[i][j] = zero4;

  const int nK = K / BKX;   // even (>= 16) for all launches here

  // prologue: tile0 (4 halves) + tile1 hA0,hB0; drain tile0 (leave 4 in flight)
  stA(0, 0, 0); stB(0, 0, 0); stA(0, 0, 1); stB(0, 0, 1);
  stA(1, 32768, 0); stB(1, 32768, 0);
  { asm volatile("s_waitcnt vmcnt(4)" ::: "memory"); }
  __builtin_amdgcn_s_barrier();

  // stage schedule (verified ledger r13):
  //   P1 hA1(T0+1) P2 hB1(T0+1) P3 hA0(T0+2) P4 hB0(T0+2)
  //   P5 hA1(T0+2) P6 hB1(T0+2) P7 hA0(T0+3) P8 hB0(T0+3)
#define STEP(STG) { \
    rdFA(0, 0); rdFB(0, 0, fbq0); stA(T0 + 1, 32768, 1);              /* P1 */ \
    VMCNT6; PH_BAR; MM16(0, 0, fbq0); \
    rdFB(0, 1, fbq1); stB(T0 + 1, 32768, 1);                          /* P2 */ \
    PH_BAR; MM16(0, 1, fbq1); \
    rdFA(0, 1); if (STG) stA(T0 + 2, 0, 0);                           /* P3 */ \
    PH_BAR; MM16(1, 0, fbq0); \
    if (STG) stB(T0 + 2, 0, 0);                                       /* P4 */ \
    MM16(1, 1, fbq1); \
    if (STG) { VMCNT8 } else { VMCNT0 } \
    BARONLY; \
    rdFA(32768, 0); rdFB(32768, 0, fbq0); if (STG) stA(T0 + 2, 0, 1); /* P5 */ \
    VMCNT6; PH_BAR; MM16(0, 0, fbq0); \
    rdFB(32768, 1, fbq1); if (STG) stB(T0 + 2, 0, 1);                 /* P6 */ \
    PH_BAR; MM16(0, 1, fbq1); \
    rdFA(32768, 1); if (STG) stA(T0 + 3, 32768, 0);                   /* P7 */ \
    PH_BAR; MM16(1, 0, fbq0); \
    if (STG) stB(T0 + 3, 32768, 0);                                   /* P8 */ \
    MM16(1, 1, fbq1); \
    if (STG) { VMCNT8 } \
    BARONLY; \
  }

  int T0 = 0;
  for (; T0 + 2 < nK; T0 += 2) STEP(1);
  STEP(0);
#undef STEP

  // ---- LDS-staged coalesced epilogue ----
  __builtin_amdgcn_s_barrier();   // all waves past K-loop; loads drained (tail vmcnt0)
  bf16* ct = (bf16*)ldsbuf;       // [256][256] bf16 = 128KB
  const bool vblk = (EPI == 6) && ((colBase >> 10) == 2);
#pragma unroll
  for (int j = 0; j < 4; ++j) {
    const int lcol = wn * 64 + (j >> 1) * 32 + (j & 1) * 16 + lr;
    float bv = 0.f;
    if constexpr (EPI == 6) {
      const int gcol = colBase + lcol;
      const int c = gcol & 1023;
      const int cb = gcol >> 10;
      bv = (cb == 0 ? bias : (cb == 1 ? bias2 : bias3))[c];
    } else if constexpr (EPI == 3) {
      bv = bias[colBase + lcol];
    }
#pragma unroll
    for (int i = 0; i < 8; ++i) {
      const int lrow0 = wm * 128 + (i >> 2) * 64 + (i & 3) * 16 + g * 4;
      if (vblk) {
        bf16x4 pv;
#pragma unroll
        for (int rr2 = 0; rr2 < 4; ++rr2) pv[rr2] = (bf16)(acc[i][j][rr2] + bv);
        *(bf16x4*)&ct[lcol * 256 + (lrow0 ^ (((lcol >> 2) & 3) << 4))] = pv;
      } else {
#pragma unroll
        for (int rr2 = 0; rr2 < 4; ++rr2) {
          const int lrow = lrow0 + rr2;
          float v = acc[i][j][rr2];
          if constexpr (EPI == 5) {
            v *= scale;
          } else if constexpr (EPI == 8) {
            v = __expf(v * scale);
          } else if constexpr (EPI == 9) {
            v *= bias[zb * 2048 + rowBase + lrow];   // linv
          } else {
            v += bv;
          }
          if constexpr (EPI == 3) v = v > 0.f ? v : 0.f;
          ct[lrow * 256 + (lcol ^ (((lrow >> 2) & 3) << 4))] = (bf16)v;
        }
      }
    }
  }
  __syncthreads();
  // coalesced store: 16 passes, each instr reads a full swizzled ct row
  bf16* dstB; int ldst; long long rowG, colG;
  if constexpr (EPI == 6) {
    const int cb = colBase >> 10;
    if (cb == 2) {
      dstB = (bf16*)out3 + (long long)(rowBase >> 11) * EMBED * SEQ;
      ldst = SEQ; rowG = colBase & 1023; colG = rowBase & (SEQ - 1);
    } else {
      dstB = (cb == 0 ? (bf16*)out : (bf16*)out2);
      ldst = EMBED; rowG = rowBase; colG = colBase & 1023;
    }
  } else if constexpr (EPI == 5 || EPI == 8 || EPI == 9) {
    dstB = (bf16*)out + (long long)zb * sOz + (long long)kh * sOk;
    ldst = ldo; rowG = rowBase; colG = colBase;
  } else {
    dstB = (bf16*)out; ldst = ldo; rowG = rowBase; colG = colBase;
  }
  const int srow = tid >> 5, sc = tid & 31;
#pragma unroll
  for (int p = 0; p < 16; ++p) {
    const int row = p * 16 + srow;
    bf16x8 vrow = *(const bf16x8*)((const char*)ct + row * 512 + ((sc * 16) ^ (((row >> 2) & 3) << 5)));
    *(bf16x8*)(dstB + (long long)(rowG + row) * ldst + colG + sc * 8) = vrow;
    if constexpr (EPI == 8) {
      // per-row expsum partial over this block's 256 cols
      float rs2 = 0.f;
#pragma unroll
      for (int q = 0; q < 8; ++q) rs2 += (float)vrow[q];
#pragma unroll
      for (int off = 1; off < 32; off <<= 1) rs2 += __shfl_xor(rs2, off);
      if (sc == 0)
        ((float*)out2)[((long long)zb * 8 + (colBase >> 8)) * 2048 + rowG + row] = rs2;
    }
  }
}

// ---------------- LayerNorm: out = LN(Xb + X2b [+cb] + Rb) * g + b ----------------
__global__ __launch_bounds__(256) void ln_kernel(const bf16* __restrict__ Xb,
                                                 const bf16* __restrict__ X2b,
                                                 const bf16* __restrict__ Rb,
                                                 const float* __restrict__ cb,
                                                 const float* __restrict__ gm,
                                                 const float* __restrict__ bt,
                                                 float* __restrict__ of,
                                                 bf16* __restrict__ ob) {
  const size_t row = blockIdx.x;
  const int t = threadIdx.x;
  bf16x4 xv = *(const bf16x4*)(Xb + row * EMBED + (size_t)t * 4);
  bf16x4 rv = *(const bf16x4*)(Rb + row * EMBED + (size_t)t * 4);
  float4 v;
  v.x = (float)xv[0] + (float)rv[0];
  v.y = (float)xv[1] + (float)rv[1];
  v.z = (float)xv[2] + (float)rv[2];
  v.w = (float)xv[3] + (float)rv[3];
  if (X2b) {
    bf16x4 x2 = *(const bf16x4*)(X2b + row * EMBED + (size_t)t * 4);
    v.x += (float)x2[0]; v.y += (float)x2[1]; v.z += (float)x2[2]; v.w += (float)x2[3];
  }
  if (cb) {
    float4 c4 = ((const float4*)cb)[t];
    v.x += c4.x; v.y += c4.y; v.z += c4.z; v.w += c4.w;
  }
  float s  = v.x + v.y + v.z + v.w;
  float ss = v.x * v.x + v.y * v.y + v.z * v.z + v.w * v.w;
#pragma unroll
  for (int o = 32; o; o >>= 1) { s += __shfl_xor(s, o); ss += __shfl_xor(ss, o); }
  __shared__ float red[8];
  const int w = t >> 6;
  if ((t & 63) == 0) { red[w] = s; red[4 + w] = ss; }
  __syncthreads();
  s  = red[0] + red[1] + red[2] + red[3];
  ss = red[4] + red[5] + red[6] + red[7];
  const float mu  = s * (1.0f / EMBED);
  const float inv = rsqrtf(ss * (1.0f / EMBED) - mu * mu + 1e-5f);
  float4 gv = ((const float4*)gm)[t];
  float4 bv = ((const float4*)bt)[t];
  float4 o4;
  o4.x = (v.x - mu) * inv * gv.x + bv.x;
  o4.y = (v.y - mu) * inv * gv.y + bv.y;
  o4.z = (v.z - mu) * inv * gv.z + bv.z;
  o4.w = (v.w - mu) * inv * gv.w + bv.w;
  if (of) ((float4*)(of + row * EMBED))[t] = o4;
  if (ob) {
    bf16x4 p;
    p[0] = (bf16)o4.x; p[1] = (bf16)o4.y; p[2] = (bf16)o4.z; p[3] = (bf16)o4.w;
    *(bf16x4*)(ob + row * EMBED + (size_t)t * 4) = p;
  }
}

// ---------------- launch ----------------
extern "C" void kernel_launch(void* const* d_in, const int* in_sizes, int n_in,
                              void* d_out, int out_size, void* d_ws, size_t ws_size,
                              hipStream_t stream) {
  const float* x   = (const float*)d_in[0];
  const float* Wq  = (const float*)d_in[1];
  const float* bq  = (const float*)d_in[2];
  const float* Wk  = (const float*)d_in[3];
  const float* bk  = (const float*)d_in[4];
  const float* Wv  = (const float*)d_in[5];
  const float* bv  = (const float*)d_in[6];
  const float* W1  = (const float*)d_in[7];
  const float* b1  = (const float*)d_in[8];
  const float* W2  = (const float*)d_in[9];
  const float* b2  = (const float*)d_in[10];
  const float* g1  = (const float*)d_in[11];
  const float* be1 = (const float*)d_in[12];
  const float* g2  = (const float*)d_in[13];
  const float* be2 = (const float*)d_in[14];
  float* out = (float*)d_out;
  char* ws = (char*)d_ws;

  bf16*  hb   = (bf16*)(ws + OFF_HB);
  bf16*  xpeb = (bf16*)(ws + OFF_XPE_B);
  bf16*  Qb   = (bf16*)(ws + OFF_Q);
  bf16*  Kb   = (bf16*)(ws + OFF_K);
  bf16*  VT   = (bf16*)(ws + OFF_VT);
  bf16*  E    = (bf16*)(ws + OFF_E);      // exp(QK/32), unnormalized
  bf16*  pv0  = (bf16*)(ws + OFF_PV0);
  bf16*  pv1  = (bf16*)(ws + OFF_PV1);
  bf16*  T1   = (bf16*)(ws + OFF_E);      // FF1 out (E dead after PV)
  bf16*  ff0  = (bf16*)(ws + OFF_PV0);    // FF2 part 0 (pv0 dead after LN1)
  bf16*  ff1  = (bf16*)(ws + OFF_Q);      // FF2 part 1 (Qb dead after QK^T)
  float* RS   = (float*)(ws + OFF_RS);
  float* LINV = (float*)(ws + OFF_LINV);
  bf16*  WqkvT = (bf16*)(ws + OFF_WQKVT);
  bf16*  W1T  = (bf16*)(ws + OFF_W1T);
  bf16*  W2T  = (bf16*)(ws + OFF_W2T);

  const long long sOk_pv = ((long long)OFF_PV1 - (long long)OFF_PV0) / 2;   // pv1 - pv0
  const long long sOk_ff = ((long long)OFF_Q - (long long)OFF_PV0) / 2;     // ff1 - ff0

  const dim3 tb(32, 8);
  transpose_kernel<<<dim3(EMBED / 32, EMBED / 32), tb, 0, stream>>>(Wq, WqkvT, EMBED, EMBED);
  transpose_kernel<<<dim3(EMBED / 32, EMBED / 32), tb, 0, stream>>>(Wk, WqkvT + (size_t)EMBED * EMBED, EMBED, EMBED);
  transpose_kernel<<<dim3(EMBED / 32, EMBED / 32), tb, 0, stream>>>(Wv, WqkvT + 2ull * EMBED * EMBED, EMBED, EMBED);
  transpose_kernel<<<dim3(FFDIM / 32, EMBED / 32), tb, 0, stream>>>(W1, W1T, EMBED, FFDIM);
  transpose_kernel<<<dim3(EMBED / 32, FFDIM / 32), tb, 0, stream>>>(W2, W2T, FFDIM, EMBED);

  pe_add_kernel<<<(SEQ * 512) / 256, 256, 0, stream>>>(x, xpeb);

  // fused QKV: Q,K row-major; V written directly as VT (384 blocks)
  gemm8_kernel<6><<<dim3(3072 / BNX, MTOK / BMX, 1), 512, 0, stream>>>(
      xpeb, WqkvT, bq, Qb, EMBED, EMBED, EMBED, EMBED, 1,
      0, 0, 0, 0, 0, 0, 1.0f, bk, bv, Kb, VT);

  // QK^T: E = exp(Q @ K^T / 32), + expsum partials -> RS  (256 blocks)
  gemm8_kernel<8><<<dim3(SEQ / BNX, SEQ / BMX, BATCH), 512, 0, stream>>>(
      Qb, Kb, nullptr, E, EMBED, EMBED, EMBED, SEQ, BATCH,
      (long long)SEQ * EMBED, (long long)SEQ * EMBED, (long long)SEQ * SEQ,
      0, 0, 0, 0.03125f, nullptr, nullptr, RS, nullptr);

  // linv = 1 / rowsum
  rowsum_inv_kernel<<<MTOK / 256, 256, 0, stream>>>(RS, LINV);

  // PV split-K: pv = (E @ VT^T) * linv[row]; K=2048 -> 2x1024, bf16 partials (256 blocks)
  gemm8_kernel<9><<<dim3(EMBED / BNX, SEQ / BMX, BATCH * 2), 512, 0, stream>>>(
      E, VT, LINV, pv0, 1024, SEQ, SEQ, EMBED, BATCH,
      (long long)SEQ * SEQ, (long long)EMBED * SEQ, (long long)SEQ * EMBED,
      1024, 1024, sOk_pv,
      1.0f, nullptr, nullptr, nullptr, nullptr);

  // hb = bf16(LN(pv0 + pv1 + xpeb))
  ln_kernel<<<MTOK, 256, 0, stream>>>(pv0, pv1, xpeb, nullptr, g1, be1, nullptr, hb);

  // FF1: relu(hb @ W1 + b1)  (512 blocks)
  gemm8_kernel<3><<<dim3(FFDIM / BNX, MTOK / BMX, 1), 512, 0, stream>>>(
      hb, W1T, b1, T1, EMBED, EMBED, EMBED, FFDIM, 1,
      0, 0, 0, 0, 0, 0, 1.0f, nullptr, nullptr, nullptr, nullptr);

  // FF2 split-K: K=4096 -> 2x2048, bf16 partials (256 blocks); bias folded into LN2
  gemm8_kernel<5><<<dim3(EMBED / BNX, MTOK / BMX, 2), 512, 0, stream>>>(
      T1, W2T, nullptr, ff0, 2048, FFDIM, FFDIM, EMBED, 1,
      0, 0, 0,
      2048, 2048, sOk_ff,
      1.0f, nullptr, nullptr, nullptr, nullptr);

  // out = LN(ff0 + ff1 + b2 + hb)
  ln_kernel<<<MTOK, 256, 0, stream>>>(ff0, ff1, hb, b2, g2, be2, out, nullptr);
}

// Round 19
// 312.440 us; speedup vs baseline: 1.0649x; 1.0273x over previous
//
#include <hip/hip_runtime.h>
#include <hip/hip_bf16.h>
#include <cmath>
#include <cstdint>

typedef __bf16 bf16;
typedef __bf16 bf16x8 __attribute__((ext_vector_type(8)));
typedef __bf16 bf16x4 __attribute__((ext_vector_type(4)));
typedef float  f32x4  __attribute__((ext_vector_type(4)));

#define EMBED 1024
#define FFDIM 4096
#define BATCH 4
#define SEQ   2048
#define MTOK  (BATCH*SEQ)

// ---------------- workspace layout ----------------
static constexpr size_t OFF_HB    = 0;              // 16MB bf16 hb (LN1 w; FF1,LN2 r)
static constexpr size_t OFF_XPE_B = 32ull << 20;    // 16MB bf16 xpeb (PE w; QKV,LN1 r)
static constexpr size_t OFF_Q     = 48ull << 20;    // Qb 16MB; later ff1 bf16 (Qb dead after QK^T)
static constexpr size_t OFF_K     = 64ull << 20;
static constexpr size_t OFF_VT    = 80ull << 20;    // 16MB bf16 [4][1024][2048] — written directly by QKV
static constexpr size_t OFF_E     = 96ull << 20;    // Eexp bf16 32MB (96-128); later T1 bf16 64MB (96-160)
static constexpr size_t OFF_PV0   = 160ull << 20;   // pv0 bf16 16MB; later ff0 bf16
static constexpr size_t OFF_PV1   = 176ull << 20;   // pv1 bf16 16MB (must not alias Eexp while PV runs)
static constexpr size_t OFF_RS    = 192ull << 20;   // row-sum partials f32 [4][8][2048] = 256KB
static constexpr size_t OFF_LINV  = 200ull << 20;   // 1/rowsum f32 [4][2048] = 32KB
static constexpr size_t OFF_WQKVT = 224ull << 20;   // 6MB bf16 [3072][1024]
static constexpr size_t OFF_W1T   = 230ull << 20;   // 8MB
static constexpr size_t OFF_W2T   = 238ull << 20;   // 8MB

// ---------------- wait/barrier primitives (r16 bare set, verified) ----------------
#define VMCNT6 { asm volatile("s_waitcnt vmcnt(6)" ::: "memory"); }
#define VMCNT8 { asm volatile("s_waitcnt vmcnt(8)" ::: "memory"); }
#define VMCNT0 { asm volatile("s_waitcnt vmcnt(0)" ::: "memory"); }
#define PH_BAR  { __builtin_amdgcn_s_barrier(); }
#define BARONLY { __builtin_amdgcn_s_barrier(); }

__device__ __forceinline__ void gload_lds16(const void* g, void* l) {
  __builtin_amdgcn_global_load_lds((const __attribute__((address_space(1))) void*)g,
                                   (__attribute__((address_space(3))) void*)l, 16, 0, 0);
}

// ---------------- PE add (vectorized): xb = bf16(x + pe) ----------------
// thread handles 8 consecutive elems (4 sin/cos pairs) per batch; f32x4 loads, bf16x8 store
__global__ __launch_bounds__(256) void pe_add_kernel(const float* __restrict__ x,
                                                     bf16* __restrict__ xb) {
  const int idx = blockIdx.x * 256 + threadIdx.x;   // SEQ*128 threads
  const int grp = idx & 127;                        // 8-elem group in row
  const int s   = idx >> 7;
  float sv[4], cv[4];
#pragma unroll
  for (int q = 0; q < 4; ++q) {
    const int pair = grp * 4 + q;
    const float div = __expf((float)(2 * pair) * (-9.210340371976184f / (float)EMBED));
    const float ang = (float)s * div;
    sv[q] = sinf(ang); cv[q] = cosf(ang);
  }
#pragma unroll
  for (int b = 0; b < BATCH; ++b) {
    const size_t base = ((size_t)(b * SEQ + s)) * EMBED + (size_t)grp * 8;
    const float4 a0 = *(const float4*)(x + base);
    const float4 a1 = *(const float4*)(x + base + 4);
    bf16x8 o;
    o[0] = (bf16)(a0.x + sv[0]); o[1] = (bf16)(a0.y + cv[0]);
    o[2] = (bf16)(a0.z + sv[1]); o[3] = (bf16)(a0.w + cv[1]);
    o[4] = (bf16)(a1.x + sv[2]); o[5] = (bf16)(a1.y + cv[2]);
    o[6] = (bf16)(a1.z + sv[3]); o[7] = (bf16)(a1.w + cv[3]);
    *(bf16x8*)(xb + base) = o;
  }
}

// ---------------- merged weight transpose: all 5 fp32[K][N] -> bf16[N][K] in one launch ----
// flat grid of 32x32 tiles; ranges: [0,1024) Wq, [1024,2048) Wk, [2048,3072) Wv,
// [3072,7168) W1 (N=4096), [7168,11264) W2 (K=4096)
__global__ __launch_bounds__(256) void transpose_all_kernel(
    const float* __restrict__ Wq, const float* __restrict__ Wk, const float* __restrict__ Wv,
    const float* __restrict__ W1, const float* __restrict__ W2,
    bf16* __restrict__ WqkvT, bf16* __restrict__ W1T, bf16* __restrict__ W2T) {
  __shared__ float tile[32][33];
  const int bid = blockIdx.x;
  const float* W; bf16* Wt; int K, N, t;
  if (bid < 3072) {
    K = EMBED; N = EMBED;
    const int which = bid >> 10;           // 0:Wq 1:Wk 2:Wv
    W  = (which == 0 ? Wq : (which == 1 ? Wk : Wv));
    Wt = WqkvT + (size_t)which * EMBED * EMBED;
    t  = bid & 1023;
  } else if (bid < 7168) {
    K = EMBED; N = FFDIM; W = W1; Wt = W1T; t = bid - 3072;
  } else {
    K = FFDIM; N = EMBED; W = W2; Wt = W2T; t = bid - 7168;
  }
  const int nbx = N >> 5;
  const int nb = (t % nbx) * 32, kb = (t / nbx) * 32;
  const int tx = threadIdx.x, ty = threadIdx.y;   // 32x8
#pragma unroll
  for (int i = 0; i < 32; i += 8)
    tile[ty + i][tx] = W[(size_t)(kb + ty + i) * N + nb + tx];
  __syncthreads();
#pragma unroll
  for (int i = 0; i < 32; i += 8)
    Wt[(size_t)(nb + ty + i) * K + kb + tx] = (bf16)tile[tx][ty + i];
}

// ---------------- rowsum reduce: linv[b][row] = 1 / sum_cb rs[b][cb][row] ----------------
__global__ __launch_bounds__(256) void rowsum_inv_kernel(const float* __restrict__ rs,
                                                         float* __restrict__ linv) {
  const int idx = blockIdx.x * 256 + threadIdx.x;   // 0..8191
  const int b = idx >> 11, row = idx & 2047;
  const float* p = rs + ((long long)b * 8) * 2048 + row;
  float s = 0.f;
#pragma unroll
  for (int cb = 0; cb < 8; ++cb) s += p[cb * 2048];
  linv[idx] = 1.0f / s;
}

// ---------------- gemm8: 256x256 tile, 8 waves (2Mx4N), 8-phase counted-vmcnt ----------------
// EPI 3: bf16 +bias relu (FF1)     EPI 5: bf16 *scale (+batch +split-K) (FF2)
// EPI 6: fused QKV (Q,K row-major; V written d-major -> VT directly)
// EPI 8: QK^T: bf16 exp(acc*scale), + per-(batch,colblock,row) expsum partials -> out2
// EPI 9: PV:   bf16 acc * linv[batch*2048+row]  (linv passed via bias)
#define BMX 256
#define BNX 256
#define BKX 64

#define MM16(QR, QC, FB) { \
  __builtin_amdgcn_s_setprio(1); \
  _Pragma("unroll") for (int kk = 0; kk < 2; ++kk) \
  _Pragma("unroll") for (int i2 = 0; i2 < 4; ++i2) \
  _Pragma("unroll") for (int j2 = 0; j2 < 2; ++j2) \
    acc[(QR)*4 + i2][(QC)*2 + j2] = __builtin_amdgcn_mfma_f32_16x16x32_bf16( \
        fa[kk][i2], FB[kk][j2], acc[(QR)*4 + i2][(QC)*2 + j2], 0, 0, 0); \
  __builtin_amdgcn_s_setprio(0); }

template <int EPI>
__global__ __launch_bounds__(512, 2) void gemm8_kernel(
    const bf16* __restrict__ A, const bf16* __restrict__ B,
    const float* __restrict__ bias, void* __restrict__ out,
    int K, int lda, int ldb, int ldo, int NB,
    long long sAz, long long sBz, long long sOz,
    long long sAk, long long sBk, long long sOk,
    float scale,
    const float* bias2, const float* bias3, void* out2, void* out3) {
  __shared__ __align__(16) char ldsbuf[131072];
  char* const ldsA = ldsbuf;            // 2buf x 32KB
  char* const ldsB = ldsbuf + 65536;    // 2buf x 32KB

  // T1: bijective XCD-chunked swizzle + grouped raster (G=8)
  const int gx = gridDim.x, gy = gridDim.y;
  int id = blockIdx.x + gx * (blockIdx.y + gy * blockIdx.z);
  const int nwg = gx * gy * gridDim.z;
  const int qd = nwg >> 3, rm = nwg & 7;
  const int xcd = id & 7, pos = id >> 3;
  const int lid = (xcd < rm ? xcd * (qd + 1) : rm * (qd + 1) + (xcd - rm) * qd) + pos;
  const int per = gx * gy;
  const int tz = lid / per;
  const int s2 = lid - tz * per;
  const int G = 8;
  const int ngrp = G * gy;
  const int grp = s2 / ngrp;
  const int within = s2 - grp * ngrp;
  const int gwf = gx - grp * G;
  const int gw = gwf < G ? gwf : G;
  const int tx = grp * G + within % gw;
  const int ty = within / gw;

  const int zb = tz % NB;
  const int kh = tz / NB;
  A += (long long)zb * sAz + (long long)kh * sAk;
  B += (long long)zb * sBz + (long long)kh * sBk;

  const int tid  = threadIdx.x;
  const int wave = tid >> 6;
  const int lane = tid & 63;
  const int wm = wave >> 2, wn = wave & 3;   // 2M x 4N
  const int rowBase = ty * BMX;
  const int colBase = tx * BNX;
  const int lr = lane & 15;
  const int g  = lane >> 4;
  const int lx = lr & 7;

  // staging: thread t -> rr = t>>3, slot (t&7)^(rr&7) (src pre-swizzled, rule 21)
  const int rr = tid >> 3;
  const int slot = (tid & 7) ^ (rr & 7);
  const bf16* Abase = A + (long long)(rowBase + rr) * lda + slot * 8;
  const bf16* Bb0 = B + (long long)(colBase + (rr & 31) + ((rr >> 5)) * 64) * ldb + slot * 8;
  const bf16* Bb1 = B + (long long)(colBase + (rr & 31) + (2 + (rr >> 5)) * 64) * ldb + slot * 8;

  auto stA = [&](int T, int bufOff, int qr) {
    char* dst = ldsA + bufOff + qr * 16384 + wave * 1024;
    const bf16* s = Abase + (long long)(qr * 64) * lda + (long long)T * BKX;
    gload_lds16(s, dst);
    gload_lds16(s + (long long)128 * lda, dst + 8192);
  };
  auto stB = [&](int T, int bufOff, int qc) {
    char* dst = ldsB + bufOff + qc * 16384 + wave * 1024;
    const long long off = (long long)(qc * 32) * ldb + (long long)T * BKX;
    gload_lds16(Bb0 + off, dst);
    gload_lds16(Bb1 + off, dst + 8192);
  };

  bf16x8 fa[2][4], fbq0[2][2], fbq1[2][2];
  auto rdFA = [&](int bufOff, int qr) {
    const char* base = ldsA + bufOff + qr * 16384 + wm * 8192;
#pragma unroll
    for (int kk = 0; kk < 2; ++kk) {
      const int sw = ((kk * 4 + g) ^ lx) << 4;
#pragma unroll
      for (int i2 = 0; i2 < 4; ++i2)
        fa[kk][i2] = *(const bf16x8*)(base + (i2 * 16 + lr) * 128 + sw);
    }
  };
  auto rdFB = [&](int bufOff, int qc, bf16x8 fb[2][2]) {
    const char* base = ldsB + bufOff + qc * 16384 + wn * 4096;
#pragma unroll
    for (int kk = 0; kk < 2; ++kk) {
      const int sw = ((kk * 4 + g) ^ lx) << 4;
#pragma unroll
      for (int j2 = 0; j2 < 2; ++j2)
        fb[kk][j2] = *(const bf16x8*)(base + (j2 * 16 + lr) * 128 + sw);
    }
  };

  const f32x4 zero4 = {0.f, 0.f, 0.f, 0.f};
  f32x4 acc[8][4];
#pragma unroll
  for (int i = 0; i < 8; ++i)
#pragma unroll
    for (int j = 0; j < 4; ++j) acc[i][j] = zero4;

  const int nK = K / BKX;   // even (>= 16) for all launches here

  // prologue: tile0 (4 halves) + tile1 hA0,hB0; drain tile0 (leave 4 in flight)
  stA(0, 0, 0); stB(0, 0, 0); stA(0, 0, 1); stB(0, 0, 1);
  stA(1, 32768, 0); stB(1, 32768, 0);
  { asm volatile("s_waitcnt vmcnt(4)" ::: "memory"); }
  __builtin_amdgcn_s_barrier();

  // stage schedule (verified ledger r13):
  //   P1 hA1(T0+1) P2 hB1(T0+1) P3 hA0(T0+2) P4 hB0(T0+2)
  //   P5 hA1(T0+2) P6 hB1(T0+2) P7 hA0(T0+3) P8 hB0(T0+3)
#define STEP(STG) { \
    rdFA(0, 0); rdFB(0, 0, fbq0); stA(T0 + 1, 32768, 1);              /* P1 */ \
    VMCNT6; PH_BAR; MM16(0, 0, fbq0); \
    rdFB(0, 1, fbq1); stB(T0 + 1, 32768, 1);                          /* P2 */ \
    PH_BAR; MM16(0, 1, fbq1); \
    rdFA(0, 1); if (STG) stA(T0 + 2, 0, 0);                           /* P3 */ \
    PH_BAR; MM16(1, 0, fbq0); \
    if (STG) stB(T0 + 2, 0, 0);                                       /* P4 */ \
    MM16(1, 1, fbq1); \
    if (STG) { VMCNT8 } else { VMCNT0 } \
    BARONLY; \
    rdFA(32768, 0); rdFB(32768, 0, fbq0); if (STG) stA(T0 + 2, 0, 1); /* P5 */ \
    VMCNT6; PH_BAR; MM16(0, 0, fbq0); \
    rdFB(32768, 1, fbq1); if (STG) stB(T0 + 2, 0, 1);                 /* P6 */ \
    PH_BAR; MM16(0, 1, fbq1); \
    rdFA(32768, 1); if (STG) stA(T0 + 3, 32768, 0);                   /* P7 */ \
    PH_BAR; MM16(1, 0, fbq0); \
    if (STG) stB(T0 + 3, 32768, 0);                                   /* P8 */ \
    MM16(1, 1, fbq1); \
    if (STG) { VMCNT8 } \
    BARONLY; \
  }

  int T0 = 0;
  for (; T0 + 2 < nK; T0 += 2) STEP(1);
  STEP(0);
#undef STEP

  // ---- LDS-staged coalesced epilogue ----
  __builtin_amdgcn_s_barrier();   // all waves past K-loop; loads drained (tail vmcnt0)
  bf16* ct = (bf16*)ldsbuf;       // [256][256] bf16 = 128KB
  const bool vblk = (EPI == 6) && ((colBase >> 10) == 2);
#pragma unroll
  for (int j = 0; j < 4; ++j) {
    const int lcol = wn * 64 + (j >> 1) * 32 + (j & 1) * 16 + lr;
    float bv = 0.f;
    if constexpr (EPI == 6) {
      const int gcol = colBase + lcol;
      const int c = gcol & 1023;
      const int cb = gcol >> 10;
      bv = (cb == 0 ? bias : (cb == 1 ? bias2 : bias3))[c];
    } else if constexpr (EPI == 3) {
      bv = bias[colBase + lcol];
    }
#pragma unroll
    for (int i = 0; i < 8; ++i) {
      const int lrow0 = wm * 128 + (i >> 2) * 64 + (i & 3) * 16 + g * 4;
      if (vblk) {
        bf16x4 pv;
#pragma unroll
        for (int rr2 = 0; rr2 < 4; ++rr2) pv[rr2] = (bf16)(acc[i][j][rr2] + bv);
        *(bf16x4*)&ct[lcol * 256 + (lrow0 ^ (((lcol >> 2) & 3) << 4))] = pv;
      } else {
#pragma unroll
        for (int rr2 = 0; rr2 < 4; ++rr2) {
          const int lrow = lrow0 + rr2;
          float v = acc[i][j][rr2];
          if constexpr (EPI == 5) {
            v *= scale;
          } else if constexpr (EPI == 8) {
            v = __expf(v * scale);
          } else if constexpr (EPI == 9) {
            v *= bias[zb * 2048 + rowBase + lrow];   // linv
          } else {
            v += bv;
          }
          if constexpr (EPI == 3) v = v > 0.f ? v : 0.f;
          ct[lrow * 256 + (lcol ^ (((lrow >> 2) & 3) << 4))] = (bf16)v;
        }
      }
    }
  }
  __syncthreads();
  // coalesced store: 16 passes, each instr reads a full swizzled ct row
  bf16* dstB; int ldst; long long rowG, colG;
  if constexpr (EPI == 6) {
    const int cb = colBase >> 10;
    if (cb == 2) {
      dstB = (bf16*)out3 + (long long)(rowBase >> 11) * EMBED * SEQ;
      ldst = SEQ; rowG = colBase & 1023; colG = rowBase & (SEQ - 1);
    } else {
      dstB = (cb == 0 ? (bf16*)out : (bf16*)out2);
      ldst = EMBED; rowG = rowBase; colG = colBase & 1023;
    }
  } else if constexpr (EPI == 5 || EPI == 8 || EPI == 9) {
    dstB = (bf16*)out + (long long)zb * sOz + (long long)kh * sOk;
    ldst = ldo; rowG = rowBase; colG = colBase;
  } else {
    dstB = (bf16*)out; ldst = ldo; rowG = rowBase; colG = colBase;
  }
  const int srow = tid >> 5, sc = tid & 31;
#pragma unroll
  for (int p = 0; p < 16; ++p) {
    const int row = p * 16 + srow;
    bf16x8 vrow = *(const bf16x8*)((const char*)ct + row * 512 + ((sc * 16) ^ (((row >> 2) & 3) << 5)));
    *(bf16x8*)(dstB + (long long)(rowG + row) * ldst + colG + sc * 8) = vrow;
    if constexpr (EPI == 8) {
      float rs2 = 0.f;
#pragma unroll
      for (int q = 0; q < 8; ++q) rs2 += (float)vrow[q];
#pragma unroll
      for (int off = 1; off < 32; off <<= 1) rs2 += __shfl_xor(rs2, off);
      if (sc == 0)
        ((float*)out2)[((long long)zb * 8 + (colBase >> 8)) * 2048 + rowG + row] = rs2;
    }
  }
}

// ---------------- LayerNorm: out = LN(Xb + X2b [+cb] + Rb) * g + b ----------------
__global__ __launch_bounds__(256) void ln_kernel(const bf16* __restrict__ Xb,
                                                 const bf16* __restrict__ X2b,
                                                 const bf16* __restrict__ Rb,
                                                 const float* __restrict__ cb,
                                                 const float* __restrict__ gm,
                                                 const float* __restrict__ bt,
                                                 float* __restrict__ of,
                                                 bf16* __restrict__ ob) {
  const size_t row = blockIdx.x;
  const int t = threadIdx.x;
  bf16x4 xv = *(const bf16x4*)(Xb + row * EMBED + (size_t)t * 4);
  bf16x4 rv = *(const bf16x4*)(Rb + row * EMBED + (size_t)t * 4);
  float4 v;
  v.x = (float)xv[0] + (float)rv[0];
  v.y = (float)xv[1] + (float)rv[1];
  v.z = (float)xv[2] + (float)rv[2];
  v.w = (float)xv[3] + (float)rv[3];
  if (X2b) {
    bf16x4 x2 = *(const bf16x4*)(X2b + row * EMBED + (size_t)t * 4);
    v.x += (float)x2[0]; v.y += (float)x2[1]; v.z += (float)x2[2]; v.w += (float)x2[3];
  }
  if (cb) {
    float4 c4 = ((const float4*)cb)[t];
    v.x += c4.x; v.y += c4.y; v.z += c4.z; v.w += c4.w;
  }
  float s  = v.x + v.y + v.z + v.w;
  float ss = v.x * v.x + v.y * v.y + v.z * v.z + v.w * v.w;
#pragma unroll
  for (int o = 32; o; o >>= 1) { s += __shfl_xor(s, o); ss += __shfl_xor(ss, o); }
  __shared__ float red[8];
  const int w = t >> 6;
  if ((t & 63) == 0) { red[w] = s; red[4 + w] = ss; }
  __syncthreads();
  s  = red[0] + red[1] + red[2] + red[3];
  ss = red[4] + red[5] + red[6] + red[7];
  const float mu  = s * (1.0f / EMBED);
  const float inv = rsqrtf(ss * (1.0f / EMBED) - mu * mu + 1e-5f);
  float4 gv = ((const float4*)gm)[t];
  float4 bv = ((const float4*)bt)[t];
  float4 o4;
  o4.x = (v.x - mu) * inv * gv.x + bv.x;
  o4.y = (v.y - mu) * inv * gv.y + bv.y;
  o4.z = (v.z - mu) * inv * gv.z + bv.z;
  o4.w = (v.w - mu) * inv * gv.w + bv.w;
  if (of) ((float4*)(of + row * EMBED))[t] = o4;
  if (ob) {
    bf16x4 p;
    p[0] = (bf16)o4.x; p[1] = (bf16)o4.y; p[2] = (bf16)o4.z; p[3] = (bf16)o4.w;
    *(bf16x4*)(ob + row * EMBED + (size_t)t * 4) = p;
  }
}

// ---------------- launch ----------------
extern "C" void kernel_launch(void* const* d_in, const int* in_sizes, int n_in,
                              void* d_out, int out_size, void* d_ws, size_t ws_size,
                              hipStream_t stream) {
  const float* x   = (const float*)d_in[0];
  const float* Wq  = (const float*)d_in[1];
  const float* bq  = (const float*)d_in[2];
  const float* Wk  = (const float*)d_in[3];
  const float* bk  = (const float*)d_in[4];
  const float* Wv  = (const float*)d_in[5];
  const float* bv  = (const float*)d_in[6];
  const float* W1  = (const float*)d_in[7];
  const float* b1  = (const float*)d_in[8];
  const float* W2  = (const float*)d_in[9];
  const float* b2  = (const float*)d_in[10];
  const float* g1  = (const float*)d_in[11];
  const float* be1 = (const float*)d_in[12];
  const float* g2  = (const float*)d_in[13];
  const float* be2 = (const float*)d_in[14];
  float* out = (float*)d_out;
  char* ws = (char*)d_ws;

  bf16*  hb   = (bf16*)(ws + OFF_HB);
  bf16*  xpeb = (bf16*)(ws + OFF_XPE_B);
  bf16*  Qb   = (bf16*)(ws + OFF_Q);
  bf16*  Kb   = (bf16*)(ws + OFF_K);
  bf16*  VT   = (bf16*)(ws + OFF_VT);
  bf16*  E    = (bf16*)(ws + OFF_E);      // exp(QK/32), unnormalized
  bf16*  pv0  = (bf16*)(ws + OFF_PV0);
  bf16*  pv1  = (bf16*)(ws + OFF_PV1);
  bf16*  T1   = (bf16*)(ws + OFF_E);      // FF1 out (E dead after PV)
  bf16*  ff0  = (bf16*)(ws + OFF_PV0);    // FF2 part 0 (pv0 dead after LN1)
  bf16*  ff1  = (bf16*)(ws + OFF_Q);      // FF2 part 1 (Qb dead after QK^T)
  float* RS   = (float*)(ws + OFF_RS);
  float* LINV = (float*)(ws + OFF_LINV);
  bf16*  WqkvT = (bf16*)(ws + OFF_WQKVT);
  bf16*  W1T  = (bf16*)(ws + OFF_W1T);
  bf16*  W2T  = (bf16*)(ws + OFF_W2T);

  const long long sOk_pv = ((long long)OFF_PV1 - (long long)OFF_PV0) / 2;   // pv1 - pv0
  const long long sOk_ff = ((long long)OFF_Q - (long long)OFF_PV0) / 2;     // ff1 - ff0

  // all 5 weight transposes in one launch (11264 tiles of 32x32)
  transpose_all_kernel<<<11264, dim3(32, 8), 0, stream>>>(
      Wq, Wk, Wv, W1, W2, WqkvT, W1T, W2T);

  pe_add_kernel<<<(SEQ * 128) / 256, 256, 0, stream>>>(x, xpeb);

  // fused QKV: Q,K row-major; V written directly as VT (384 blocks)
  gemm8_kernel<6><<<dim3(3072 / BNX, MTOK / BMX, 1), 512, 0, stream>>>(
      xpeb, WqkvT, bq, Qb, EMBED, EMBED, EMBED, EMBED, 1,
      0, 0, 0, 0, 0, 0, 1.0f, bk, bv, Kb, VT);

  // QK^T: E = exp(Q @ K^T / 32), + expsum partials -> RS  (256 blocks)
  gemm8_kernel<8><<<dim3(SEQ / BNX, SEQ / BMX, BATCH), 512, 0, stream>>>(
      Qb, Kb, nullptr, E, EMBED, EMBED, EMBED, SEQ, BATCH,
      (long long)SEQ * EMBED, (long long)SEQ * EMBED, (long long)SEQ * SEQ,
      0, 0, 0, 0.03125f, nullptr, nullptr, RS, nullptr);

  // linv = 1 / rowsum
  rowsum_inv_kernel<<<MTOK / 256, 256, 0, stream>>>(RS, LINV);

  // PV split-K: pv = (E @ VT^T) * linv[row]; K=2048 -> 2x1024, bf16 partials (256 blocks)
  gemm8_kernel<9><<<dim3(EMBED / BNX, SEQ / BMX, BATCH * 2), 512, 0, stream>>>(
      E, VT, LINV, pv0, 1024, SEQ, SEQ, EMBED, BATCH,
      (long long)SEQ * SEQ, (long long)EMBED * SEQ, (long long)SEQ * EMBED,
      1024, 1024, sOk_pv,
      1.0f, nullptr, nullptr, nullptr, nullptr);

  // hb = bf16(LN(pv0 + pv1 + xpeb))
  ln_kernel<<<MTOK, 256, 0, stream>>>(pv0, pv1, xpeb, nullptr, g1, be1, nullptr, hb);

  // FF1: relu(hb @ W1 + b1)  (512 blocks)
  gemm8_kernel<3><<<dim3(FFDIM / BNX, MTOK / BMX, 1), 512, 0, stream>>>(
      hb, W1T, b1, T1, EMBED, EMBED, EMBED, FFDIM, 1,
      0, 0, 0, 0, 0, 0, 1.0f, nullptr, nullptr, nullptr, nullptr);

  // FF2 split-K: K=4096 -> 2x2048, bf16 partials (256 blocks); bias folded into LN2
  gemm8_kernel<5><<<dim3(EMBED / BNX, MTOK / BMX, 2), 512, 0, stream>>>(
      T1, W2T, nullptr, ff0, 2048, FFDIM, FFDIM, EMBED, 1,
      0, 0, 0,
      2048, 2048, sOk_ff,
      1.0f, nullptr, nullptr, nullptr, nullptr);

  // out = LN(ff0 + ff1 + b2 + hb)
  ln_kernel<<<MTOK, 256, 0, stream>>>(ff0, ff1, hb, b2, g2, be2, out, nullptr);
}